// Round 1
// baseline (365.921 us; speedup 1.0000x reference)
//
#include <hip/hip_runtime.h>

// InfiniAttention fp32 baseline — chunked linear attention formulation.
// B=4, S=1024, H=1024, D_MEM=256. All GEMMs: 64x64 tile, BK=16, 256 thr, 4x4 micro.

#define HIDDEN 1024
#define DMEM 256
#define BATCH 4
#define SEQ 1024
#define MTOT (BATCH * SEQ)      // 4096
#define CHUNK 128
#define NCH (SEQ / CHUNK)       // 8 chunks per batch
#define NCHT (BATCH * NCH)      // 32 chunks total
#define EPSF 1e-6f

__device__ __forceinline__ float elu1(float x) { return x > 0.f ? x + 1.f : __expf(x); }

// Load a BMxBK tile from row-major [rows x ld] where K is contiguous (element (m,k) at
// base[(row0+m)*ld + col0+k]) -> transpose into S[k][m].
__device__ __forceinline__ void load_MK(float S[16][68], const float* __restrict__ base,
                                        int ld, int row0, int col0, int tid) {
  int m = tid >> 2;
  int k4 = (tid & 3) << 2;
  float4 t = *reinterpret_cast<const float4*>(base + (size_t)(row0 + m) * ld + (col0 + k4));
  S[k4 + 0][m] = t.x;
  S[k4 + 1][m] = t.y;
  S[k4 + 2][m] = t.z;
  S[k4 + 3][m] = t.w;
}

// Load a BKxBN tile where N is contiguous (element (k,n) at base[(krow0+k)*ld + col0+n])
// -> direct into S[k][n].
__device__ __forceinline__ void load_KN(float S[16][68], const float* __restrict__ base,
                                        int ld, int krow0, int col0, int tid) {
  int k = tid >> 4;
  int n4 = (tid & 15) << 2;
  *reinterpret_cast<float4*>(&S[k][n4]) =
      *reinterpret_cast<const float4*>(base + (size_t)(krow0 + k) * ld + (col0 + n4));
}

__device__ __forceinline__ void micro_mm(float As[16][68], float Bs[16][68], int tid,
                                         float acc[4][4]) {
  int ty = tid >> 4, tx = tid & 15;
#pragma unroll
  for (int k = 0; k < 16; ++k) {
    float a[4], b[4];
#pragma unroll
    for (int i = 0; i < 4; ++i) a[i] = As[k][ty * 4 + i];
#pragma unroll
    for (int j = 0; j < 4; ++j) b[j] = Bs[k][tx * 4 + j];
#pragma unroll
    for (int i = 0; i < 4; ++i)
#pragma unroll
      for (int j = 0; j < 4; ++j) acc[i][j] = fmaf(a[i], b[j], acc[i][j]);
  }
}

// ---- K1: fused QKV projection. out[m,n] = sum_h X[m,h]*W[n,h]; sigma on q,k. ----
__global__ __launch_bounds__(256) void k1_qkv(const float* __restrict__ X,
                                              const float* __restrict__ wq,
                                              const float* __restrict__ wk,
                                              const float* __restrict__ wv,
                                              float* __restrict__ sq, float* __restrict__ sk,
                                              float* __restrict__ vb) {
  __shared__ float As[16][68];
  __shared__ float Bs[16][68];
  int tid = threadIdx.x;
  int m0 = blockIdx.x * 64;
  int n0g = blockIdx.y * 64;  // 0..767
  int wsel = n0g >> 8;
  int n0 = n0g & 255;
  const float* W = (wsel == 0) ? wq : (wsel == 1 ? wk : wv);
  float acc[4][4] = {};
  for (int k0 = 0; k0 < HIDDEN; k0 += 16) {
    load_MK(As, X, HIDDEN, m0, k0, tid);
    load_MK(Bs, W, HIDDEN, n0, k0, tid);  // W is [N,K] K-contig
    __syncthreads();
    micro_mm(As, Bs, tid, acc);
    __syncthreads();
  }
  int ty = tid >> 4, tx = tid & 15;
  float* dst = (wsel == 0) ? sq : (wsel == 1 ? sk : vb);
#pragma unroll
  for (int i = 0; i < 4; ++i)
#pragma unroll
    for (int j = 0; j < 4; ++j) {
      int m = m0 + ty * 4 + i;
      int n = n0 + tx * 4 + j;
      float v = acc[i][j];
      if (wsel < 2) v = elu1(v);
      dst[(size_t)m * DMEM + n] = v;
    }
}

// ---- K2: per-chunk KV sums. kvc[c][d][e] = sum_{s in chunk} sk[s,d]*v[s,e]. ----
__global__ __launch_bounds__(256) void k2_kvchunk(const float* __restrict__ sk,
                                                  const float* __restrict__ vb,
                                                  float* __restrict__ kvc) {
  __shared__ float As[16][68];
  __shared__ float Bs[16][68];
  int tid = threadIdx.x;
  int c = blockIdx.x;
  int d0 = (blockIdx.y >> 2) * 64;
  int e0 = (blockIdx.y & 3) * 64;
  int row0 = c * CHUNK;
  float acc[4][4] = {};
  for (int kk = 0; kk < CHUNK; kk += 16) {
    load_KN(As, sk, DMEM, row0 + kk, d0, tid);  // As[s][d]
    load_KN(Bs, vb, DMEM, row0 + kk, e0, tid);  // Bs[s][e]
    __syncthreads();
    micro_mm(As, Bs, tid, acc);
    __syncthreads();
  }
  int ty = tid >> 4, tx = tid & 15;
#pragma unroll
  for (int i = 0; i < 4; ++i)
#pragma unroll
    for (int j = 0; j < 4; ++j)
      kvc[(size_t)c * DMEM * DMEM + (size_t)(d0 + ty * 4 + i) * DMEM + e0 + tx * 4 + j] =
          acc[i][j];
}

// ---- K2b: per-chunk column sums of sigma_k. ----
__global__ void k2b_ksum(const float* __restrict__ sk, float* __restrict__ ksc) {
  int c = blockIdx.x;
  int d = threadIdx.x;
  float s = 0.f;
  for (int i = 0; i < CHUNK; ++i) s += sk[(size_t)(c * CHUNK + i) * DMEM + d];
  ksc[c * DMEM + d] = s;
}

// ---- K3: exclusive prefix over chunks (kv in-place, ksum to ksp) + memnorm flag. ----
__global__ void k3_prefix(float* __restrict__ kvc, const float* __restrict__ ksc,
                          float* __restrict__ ksp, const float* __restrict__ mnorm,
                          float* __restrict__ flag) {
  int b = blockIdx.x;
  if (b < 1024) {
    int batch = b >> 8;
    int idx = (b & 255) * 256 + threadIdx.x;  // 0..65535 within [d][e]
    float run = 0.f;
    for (int c = 0; c < NCH; ++c) {
      size_t off = (size_t)(batch * NCH + c) * DMEM * DMEM + idx;
      float t = kvc[off];
      kvc[off] = run;
      run += t;
    }
  } else if (b < 1028) {
    int batch = b - 1024;
    int d = threadIdx.x;
    float run = 0.f;
    for (int c = 0; c < NCH; ++c) {
      int off = (batch * NCH + c) * DMEM + d;
      float t = ksc[off];
      ksp[off] = run;
      run += t;
    }
  } else {
    __shared__ float red[256];
    red[threadIdx.x] = mnorm[threadIdx.x];
    __syncthreads();
    for (int s = 128; s > 0; s >>= 1) {
      if (threadIdx.x < s) red[threadIdx.x] += red[threadIdx.x + s];
      __syncthreads();
    }
    if (threadIdx.x == 0) *flag = (red[0] < EPSF) ? 0.f : 1.f;
  }
}

// ---- K4a: intra-chunk causal scores. sc[c][i][j] = (j<=i) * dot(sq_i, sk_j). ----
__global__ __launch_bounds__(256) void k4a_scores(const float* __restrict__ sq,
                                                  const float* __restrict__ sk,
                                                  float* __restrict__ sc) {
  __shared__ float As[16][68];
  __shared__ float Bs[16][68];
  int tid = threadIdx.x;
  int c = blockIdx.x;
  int i0 = (blockIdx.y >> 1) * 64;
  int j0 = (blockIdx.y & 1) * 64;
  float acc[4][4] = {};
  for (int k0 = 0; k0 < DMEM; k0 += 16) {
    load_MK(As, sq, DMEM, c * CHUNK + i0, k0, tid);
    load_MK(Bs, sk, DMEM, c * CHUNK + j0, k0, tid);
    __syncthreads();
    micro_mm(As, Bs, tid, acc);
    __syncthreads();
  }
  int ty = tid >> 4, tx = tid & 15;
#pragma unroll
  for (int i = 0; i < 4; ++i)
#pragma unroll
    for (int j = 0; j < 4; ++j) {
      int ii = i0 + ty * 4 + i;
      int jj = j0 + tx * 4 + j;
      sc[(size_t)c * CHUNK * CHUNK + (size_t)ii * CHUNK + jj] = (jj <= ii) ? acc[i][j] : 0.f;
    }
}

// ---- K4p: per-row scalars: den[m], qnorm[m], knorm[m]. One wave per row. ----
__global__ __launch_bounds__(256) void k4p_rows(const float* __restrict__ sc,
                                                const float* __restrict__ sq,
                                                const float* __restrict__ sk,
                                                const float* __restrict__ ksp,
                                                const float* __restrict__ mnorm,
                                                float* __restrict__ den, float* __restrict__ qn,
                                                float* __restrict__ kn) {
  int wave = threadIdx.x >> 6;
  int lane = threadIdx.x & 63;
  int m = blockIdx.x * 4 + wave;
  int c = m / CHUNK;
  int i = m % CHUNK;
  float s_sc = 0.f, s_d2 = 0.f, s_qn = 0.f, s_kn = 0.f;
  for (int j = lane; j < CHUNK; j += 64)
    s_sc += sc[(size_t)c * CHUNK * CHUNK + (size_t)i * CHUNK + j];
  for (int d = lane; d < DMEM; d += 64) {
    float q = sq[(size_t)m * DMEM + d];
    float k = sk[(size_t)m * DMEM + d];
    s_d2 += q * ksp[c * DMEM + d];
    s_qn += q * mnorm[d];
    s_kn += k * mnorm[d];
  }
#pragma unroll
  for (int off = 32; off > 0; off >>= 1) {
    s_sc += __shfl_down(s_sc, off);
    s_d2 += __shfl_down(s_d2, off);
    s_qn += __shfl_down(s_qn, off);
    s_kn += __shfl_down(s_kn, off);
  }
  if (lane == 0) {
    den[m] = s_sc + s_d2;
    qn[m] = s_qn;
    kn[m] = s_kn;
  }
}

// ---- K4b: local output. loc[m,e] = (scores@v + sq@kv_prefix)/max(den,eps). K=128+256. ----
__global__ __launch_bounds__(256) void k4b_local(const float* __restrict__ sc,
                                                 const float* __restrict__ sq,
                                                 const float* __restrict__ vb,
                                                 const float* __restrict__ kvp,
                                                 const float* __restrict__ den,
                                                 float* __restrict__ loc) {
  __shared__ float As[16][68];
  __shared__ float Bs[16][68];
  int tid = threadIdx.x;
  int c = blockIdx.x;
  int i0 = (blockIdx.y >> 2) * 64;
  int e0 = (blockIdx.y & 3) * 64;
  float acc[4][4] = {};
  for (int k0 = 0; k0 < CHUNK; k0 += 16) {  // intra: scores @ v_chunk
    load_MK(As, sc + (size_t)c * CHUNK * CHUNK, CHUNK, i0, k0, tid);
    load_KN(Bs, vb, DMEM, c * CHUNK + k0, e0, tid);
    __syncthreads();
    micro_mm(As, Bs, tid, acc);
    __syncthreads();
  }
  for (int k0 = 0; k0 < DMEM; k0 += 16) {  // inter: sigma_q @ kv_prefix
    load_MK(As, sq, DMEM, c * CHUNK + i0, k0, tid);
    load_KN(Bs, kvp + (size_t)c * DMEM * DMEM, DMEM, k0, e0, tid);
    __syncthreads();
    micro_mm(As, Bs, tid, acc);
    __syncthreads();
  }
  int ty = tid >> 4, tx = tid & 15;
#pragma unroll
  for (int i = 0; i < 4; ++i)
#pragma unroll
    for (int j = 0; j < 4; ++j) {
      int m = c * CHUNK + i0 + ty * 4 + i;
      int e = e0 + tx * 4 + j;
      loc[(size_t)m * DMEM + e] = acc[i][j] / fmaxf(den[m], EPSF);
    }
}

// ---- K5: memory retrieval + gate combine (in place over loc). ----
__global__ __launch_bounds__(256) void k5_combine(const float* __restrict__ sq,
                                                  const float* __restrict__ mem,
                                                  const float* __restrict__ qn,
                                                  const float* __restrict__ gate,
                                                  const float* __restrict__ flag,
                                                  float* __restrict__ loc) {
  __shared__ float As[16][68];
  __shared__ float Bs[16][68];
  int tid = threadIdx.x;
  int m0 = blockIdx.x * 64;
  int n0 = blockIdx.y * 64;
  float acc[4][4] = {};
  for (int k0 = 0; k0 < DMEM; k0 += 16) {
    load_MK(As, sq, DMEM, m0, k0, tid);
    load_KN(Bs, mem, DMEM, k0, n0, tid);
    __syncthreads();
    micro_mm(As, Bs, tid, acc);
    __syncthreads();
  }
  float g = 1.f / (1.f + __expf(-gate[0]));
  float fl = *flag;
  int ty = tid >> 4, tx = tid & 15;
#pragma unroll
  for (int i = 0; i < 4; ++i)
#pragma unroll
    for (int j = 0; j < 4; ++j) {
      int m = m0 + ty * 4 + i;
      int n = n0 + tx * 4 + j;
      size_t off = (size_t)m * DMEM + n;
      float mo = fl * acc[i][j] / fmaxf(qn[m], EPSF);
      loc[off] = g * mo + (1.f - g) * loc[off];
    }
}

// ---- K6: output projection. out[m,h] = sum_d comb[m,d]*wo[h,d]. ----
__global__ __launch_bounds__(256) void k6_out(const float* __restrict__ comb,
                                              const float* __restrict__ wo,
                                              float* __restrict__ out) {
  __shared__ float As[16][68];
  __shared__ float Bs[16][68];
  int tid = threadIdx.x;
  int m0 = blockIdx.x * 64;
  int n0 = blockIdx.y * 64;
  float acc[4][4] = {};
  for (int k0 = 0; k0 < DMEM; k0 += 16) {
    load_MK(As, comb, DMEM, m0, k0, tid);
    load_MK(Bs, wo, DMEM, n0, k0, tid);  // wo is [H, D] K-contig
    __syncthreads();
    micro_mm(As, Bs, tid, acc);
    __syncthreads();
  }
  int ty = tid >> 4, tx = tid & 15;
#pragma unroll
  for (int i = 0; i < 4; ++i)
#pragma unroll
    for (int j = 0; j < 4; ++j) {
      int m = m0 + ty * 4 + i;
      int n = n0 + tx * 4 + j;
      out[(size_t)m * HIDDEN + n] = acc[i][j];
    }
}

// ---- K7a: delta_v = v - (sigma_k @ memory)/max(knorm,eps). ----
__global__ __launch_bounds__(256) void k7a_delta(const float* __restrict__ sk,
                                                 const float* __restrict__ mem,
                                                 const float* __restrict__ kn,
                                                 const float* __restrict__ vb,
                                                 float* __restrict__ dv) {
  __shared__ float As[16][68];
  __shared__ float Bs[16][68];
  int tid = threadIdx.x;
  int m0 = blockIdx.x * 64;
  int n0 = blockIdx.y * 64;
  float acc[4][4] = {};
  for (int k0 = 0; k0 < DMEM; k0 += 16) {
    load_MK(As, sk, DMEM, m0, k0, tid);
    load_KN(Bs, mem, DMEM, k0, n0, tid);
    __syncthreads();
    micro_mm(As, Bs, tid, acc);
    __syncthreads();
  }
  int ty = tid >> 4, tx = tid & 15;
#pragma unroll
  for (int i = 0; i < 4; ++i)
#pragma unroll
    for (int j = 0; j < 4; ++j) {
      int m = m0 + ty * 4 + i;
      int n = n0 + tx * 4 + j;
      size_t off = (size_t)m * DMEM + n;
      dv[off] = vb[off] - acc[i][j] / fmaxf(kn[m], EPSF);
    }
}

// ---- K7init: seed new_memory region of d_out with memory (atomics add onto it). ----
__global__ void k7init(const float* __restrict__ mem, float* __restrict__ out) {
  int i = blockIdx.x * 256 + threadIdx.x;
  if (i < DMEM * DMEM) out[(size_t)MTOT * HIDDEN + i] = mem[i];
}

// ---- K7b: memory_update split-K GEMM: out_mem[d,e] += sum_m sk[m,d]*dv[m,e]/4096. ----
__global__ __launch_bounds__(256) void k7b_update(const float* __restrict__ sk,
                                                  const float* __restrict__ dv,
                                                  float* __restrict__ out) {
  __shared__ float As[16][68];
  __shared__ float Bs[16][68];
  int tid = threadIdx.x;
  int kseg = blockIdx.x;  // 16 segments of 256 rows
  int d0 = (blockIdx.y >> 2) * 64;
  int e0 = (blockIdx.y & 3) * 64;
  int row0 = kseg * 256;
  float acc[4][4] = {};
  for (int kk = 0; kk < 256; kk += 16) {
    load_KN(As, sk, DMEM, row0 + kk, d0, tid);
    load_KN(Bs, dv, DMEM, row0 + kk, e0, tid);
    __syncthreads();
    micro_mm(As, Bs, tid, acc);
    __syncthreads();
  }
  int ty = tid >> 4, tx = tid & 15;
  float* base = out + (size_t)MTOT * HIDDEN;
#pragma unroll
  for (int i = 0; i < 4; ++i)
#pragma unroll
    for (int j = 0; j < 4; ++j)
      atomicAdd(&base[(size_t)(d0 + ty * 4 + i) * DMEM + e0 + tx * 4 + j],
                acc[i][j] * (1.f / (float)MTOT));
}

// ---- K7c: new_memory_norm = memory_norm + sum_chunks ksum / BATCH. ----
__global__ void k7c_norm(const float* __restrict__ ksc, const float* __restrict__ mnorm,
                         float* __restrict__ out) {
  int d = threadIdx.x;
  float s = 0.f;
  for (int c = 0; c < NCHT; ++c) s += ksc[c * DMEM + d];
  out[(size_t)MTOT * HIDDEN + DMEM * DMEM + d] = mnorm[d] + s * (1.f / (float)BATCH);
}

extern "C" void kernel_launch(void* const* d_in, const int* in_sizes, int n_in,
                              void* d_out, int out_size, void* d_ws, size_t ws_size,
                              hipStream_t stream) {
  const float* hs = (const float*)d_in[0];
  const float* wq = (const float*)d_in[1];
  const float* wk = (const float*)d_in[2];
  const float* wv = (const float*)d_in[3];
  const float* wo = (const float*)d_in[4];
  const float* gate = (const float*)d_in[5];
  const float* mem = (const float*)d_in[6];
  const float* mnorm = (const float*)d_in[7];
  float* out = (float*)d_out;
  float* ws = (float*)d_ws;

  // workspace layout (floats); total ~6.85M floats (~27.4 MB)
  float* sq = ws;                    // 4096*256
  float* sk = sq + MTOT * DMEM;      // 4096*256
  float* vb = sk + MTOT * DMEM;      // 4096*256
  float* kvc = vb + MTOT * DMEM;     // 32*256*256 (chunk sums, then in-place excl prefix)
  float* ksc = kvc + NCHT * DMEM * DMEM;  // 32*256
  float* ksp = ksc + NCHT * DMEM;         // 32*256
  float* scor = ksp + NCHT * DMEM;        // 32*128*128
  float* den = scor + (size_t)NCHT * CHUNK * CHUNK;  // 4096
  float* qn = den + MTOT;                            // 4096
  float* kn = qn + MTOT;                             // 4096
  float* loc = kn + MTOT;                            // 4096*256 (local, then combined)
  float* flag = loc + MTOT * DMEM;                   // 1
  float* dv = sq;  // alias: sigma_q dead after k5_combine

  k1_qkv<<<dim3(MTOT / 64, 12), 256, 0, stream>>>(hs, wq, wk, wv, sq, sk, vb);
  k2_kvchunk<<<dim3(NCHT, 16), 256, 0, stream>>>(sk, vb, kvc);
  k2b_ksum<<<dim3(NCHT), 256, 0, stream>>>(sk, ksc);
  k3_prefix<<<dim3(1029), 256, 0, stream>>>(kvc, ksc, ksp, mnorm, flag);
  k4a_scores<<<dim3(NCHT, 4), 256, 0, stream>>>(sq, sk, scor);
  k4p_rows<<<dim3(MTOT / 4), 256, 0, stream>>>(scor, sq, sk, ksp, mnorm, den, qn, kn);
  k4b_local<<<dim3(NCHT, 8), 256, 0, stream>>>(scor, sq, vb, kvc, den, loc);
  k5_combine<<<dim3(MTOT / 64, DMEM / 64), 256, 0, stream>>>(sq, mem, qn, gate, flag, loc);
  k6_out<<<dim3(MTOT / 64, HIDDEN / 64), 256, 0, stream>>>(loc, wo, out);
  k7a_delta<<<dim3(MTOT / 64, DMEM / 64), 256, 0, stream>>>(sk, mem, kn, vb, dv);
  k7init<<<dim3(DMEM * DMEM / 256), 256, 0, stream>>>(mem, out);
  k7b_update<<<dim3(16, 16), 256, 0, stream>>>(sk, dv, out);
  k7c_norm<<<dim3(1), 256, 0, stream>>>(ksc, mnorm, out);
}

// Round 2
// 261.966 us; speedup vs baseline: 1.3968x; 1.3968x over previous
//
#include <hip/hip_runtime.h>

// InfiniAttention — chunked linear attention. Round 2: QKV + out-proj on bf16 MFMA
// (16x16x32, 64x128 tile, global_load_lds width-16 staging); rest still fp32 vector.

#define HIDDEN 1024
#define DMEM 256
#define BATCH 4
#define SEQ 1024
#define MTOT (BATCH * SEQ)      // 4096
#define CHUNK 128
#define NCH (SEQ / CHUNK)       // 8
#define NCHT (BATCH * NCH)      // 32
#define EPSF 1e-6f

typedef __bf16 bf16x8 __attribute__((ext_vector_type(8)));
typedef __bf16 bf16x4 __attribute__((ext_vector_type(4)));
typedef float f32x4 __attribute__((ext_vector_type(4)));

#define GL_LDS(g, l)                                                                   \
  __builtin_amdgcn_global_load_lds((const __attribute__((address_space(1))) void*)(g), \
                                   (__attribute__((address_space(3))) void*)(l), 16, 0, 0)

__device__ __forceinline__ float elu1(float x) { return x > 0.f ? x + 1.f : __expf(x); }

// ---------------- casts ----------------
__global__ void kcast_hs(const float* __restrict__ src, __bf16* __restrict__ dst) {
  int i = blockIdx.x * 256 + threadIdx.x;  // 1048576 float4 groups
  float4 f = reinterpret_cast<const float4*>(src)[i];
  bf16x4 h = {(__bf16)f.x, (__bf16)f.y, (__bf16)f.z, (__bf16)f.w};
  reinterpret_cast<bf16x4*>(dst)[i] = h;
}

__global__ void kcast_w(const float* __restrict__ wq, const float* __restrict__ wk,
                        const float* __restrict__ wv, const float* __restrict__ wo,
                        __bf16* __restrict__ wqkvb, __bf16* __restrict__ wob) {
  int y = blockIdx.y;
  const float* src = (y == 0) ? wq : (y == 1) ? wk : (y == 2) ? wv : wo;
  __bf16* dst = (y < 3) ? wqkvb + (size_t)y * (DMEM * HIDDEN) : wob;
  int i = blockIdx.x * 256 + threadIdx.x;  // 65536 float4 groups per source
  float4 f = reinterpret_cast<const float4*>(src)[i];
  bf16x4 h = {(__bf16)f.x, (__bf16)f.y, (__bf16)f.z, (__bf16)f.w};
  reinterpret_cast<bf16x4*>(dst)[i] = h;
}

// ---------------- K1: fused QKV projection, bf16 MFMA ----------------
// C[m,n] = sum_k X[m,k]*W[n,k]; W = stacked [wq;wk;wv] as [768][1024].
// Tile 64x128, 4 waves (2x2), wave tile 32x64 (2x4 mfma tiles).
__global__ __launch_bounds__(256) void k1_qkv_mfma(const __bf16* __restrict__ X,
                                                   const __bf16* __restrict__ W,
                                                   float* __restrict__ sq,
                                                   float* __restrict__ sk,
                                                   float* __restrict__ vb) {
  __shared__ __bf16 As[64 * 32];
  __shared__ __bf16 Bs[128 * 32];
  int tid = threadIdx.x;
  int lane = tid & 63, wave = tid >> 6;
  int m0 = blockIdx.x * 64;
  int by = blockIdx.y;  // 0..5 -> n0g = by*128
  const __bf16* Wb = W + (size_t)by * 128 * HIDDEN;

  int arow = tid >> 2, acol = (tid & 3) << 3;
  const __bf16* aptr = X + (size_t)(m0 + arow) * HIDDEN + acol;
  const __bf16* bptr = Wb + (size_t)arow * HIDDEN + acol;
  __bf16* alds = As + wave * 512;
  __bf16* blds = Bs + wave * 512;

  int wr = wave >> 1, wc = wave & 1;
  int quad = lane >> 4, l16 = lane & 15;
  f32x4 acc[2][4] = {};

  for (int k0 = 0; k0 < HIDDEN; k0 += 32) {
    GL_LDS(aptr + k0, alds);
    GL_LDS(bptr + k0, blds);
    GL_LDS(bptr + 64 * HIDDEN + k0, blds + 2048);
    __syncthreads();
    bf16x8 aF[2], bF[4];
#pragma unroll
    for (int i = 0; i < 2; ++i)
      aF[i] = *reinterpret_cast<const bf16x8*>(As + (wr * 32 + i * 16 + l16) * 32 + quad * 8);
#pragma unroll
    for (int j = 0; j < 4; ++j)
      bF[j] = *reinterpret_cast<const bf16x8*>(Bs + (wc * 64 + j * 16 + l16) * 32 + quad * 8);
#pragma unroll
    for (int i = 0; i < 2; ++i)
#pragma unroll
      for (int j = 0; j < 4; ++j)
        acc[i][j] = __builtin_amdgcn_mfma_f32_16x16x32_bf16(aF[i], bF[j], acc[i][j], 0, 0, 0);
    __syncthreads();
  }

  int wsel = by >> 1;
  float* dst = (wsel == 0) ? sq : (wsel == 1) ? sk : vb;
  int nbase = (by & 1) * 128 + wc * 64;
#pragma unroll
  for (int i = 0; i < 2; ++i)
#pragma unroll
    for (int j = 0; j < 4; ++j)
#pragma unroll
      for (int r = 0; r < 4; ++r) {
        int m = m0 + wr * 32 + i * 16 + quad * 4 + r;
        int n = nbase + j * 16 + l16;
        float v = acc[i][j][r];
        if (wsel < 2) v = elu1(v);
        dst[(size_t)m * DMEM + n] = v;
      }
}

// ---------------- K6: output projection, bf16 MFMA ----------------
// out[m,h] = sum_d comb[m,d]*wo[h,d]. M=4096,N=1024,K=256.
__global__ __launch_bounds__(256) void k6_out_mfma(const __bf16* __restrict__ A,
                                                   const __bf16* __restrict__ B,
                                                   float* __restrict__ out) {
  __shared__ __bf16 As[64 * 32];
  __shared__ __bf16 Bs[128 * 32];
  int tid = threadIdx.x;
  int lane = tid & 63, wave = tid >> 6;
  int m0 = blockIdx.x * 64;
  int by = blockIdx.y;  // 0..7
  const __bf16* Bb = B + (size_t)by * 128 * DMEM;

  int arow = tid >> 2, acol = (tid & 3) << 3;
  const __bf16* aptr = A + (size_t)(m0 + arow) * DMEM + acol;
  const __bf16* bptr = Bb + (size_t)arow * DMEM + acol;
  __bf16* alds = As + wave * 512;
  __bf16* blds = Bs + wave * 512;

  int wr = wave >> 1, wc = wave & 1;
  int quad = lane >> 4, l16 = lane & 15;
  f32x4 acc[2][4] = {};

  for (int k0 = 0; k0 < DMEM; k0 += 32) {
    GL_LDS(aptr + k0, alds);
    GL_LDS(bptr + k0, blds);
    GL_LDS(bptr + 64 * DMEM + k0, blds + 2048);
    __syncthreads();
    bf16x8 aF[2], bF[4];
#pragma unroll
    for (int i = 0; i < 2; ++i)
      aF[i] = *reinterpret_cast<const bf16x8*>(As + (wr * 32 + i * 16 + l16) * 32 + quad * 8);
#pragma unroll
    for (int j = 0; j < 4; ++j)
      bF[j] = *reinterpret_cast<const bf16x8*>(Bs + (wc * 64 + j * 16 + l16) * 32 + quad * 8);
#pragma unroll
    for (int i = 0; i < 2; ++i)
#pragma unroll
      for (int j = 0; j < 4; ++j)
        acc[i][j] = __builtin_amdgcn_mfma_f32_16x16x32_bf16(aF[i], bF[j], acc[i][j], 0, 0, 0);
    __syncthreads();
  }

#pragma unroll
  for (int i = 0; i < 2; ++i)
#pragma unroll
    for (int j = 0; j < 4; ++j)
#pragma unroll
      for (int r = 0; r < 4; ++r) {
        int m = m0 + wr * 32 + i * 16 + quad * 4 + r;
        int n = by * 128 + wc * 64 + j * 16 + l16;
        out[(size_t)m * HIDDEN + n] = acc[i][j][r];
      }
}

// ---------------- fp32 tile machinery (unchanged) ----------------
__device__ __forceinline__ void load_MK(float S[16][68], const float* __restrict__ base,
                                        int ld, int row0, int col0, int tid) {
  int m = tid >> 2;
  int k4 = (tid & 3) << 2;
  float4 t = *reinterpret_cast<const float4*>(base + (size_t)(row0 + m) * ld + (col0 + k4));
  S[k4 + 0][m] = t.x;
  S[k4 + 1][m] = t.y;
  S[k4 + 2][m] = t.z;
  S[k4 + 3][m] = t.w;
}

__device__ __forceinline__ void load_KN(float S[16][68], const float* __restrict__ base,
                                        int ld, int krow0, int col0, int tid) {
  int k = tid >> 4;
  int n4 = (tid & 15) << 2;
  *reinterpret_cast<float4*>(&S[k][n4]) =
      *reinterpret_cast<const float4*>(base + (size_t)(krow0 + k) * ld + (col0 + n4));
}

__device__ __forceinline__ void micro_mm(float As[16][68], float Bs[16][68], int tid,
                                         float acc[4][4]) {
  int ty = tid >> 4, tx = tid & 15;
#pragma unroll
  for (int k = 0; k < 16; ++k) {
    float a[4], b[4];
#pragma unroll
    for (int i = 0; i < 4; ++i) a[i] = As[k][ty * 4 + i];
#pragma unroll
    for (int j = 0; j < 4; ++j) b[j] = Bs[k][tx * 4 + j];
#pragma unroll
    for (int i = 0; i < 4; ++i)
#pragma unroll
      for (int j = 0; j < 4; ++j) acc[i][j] = fmaf(a[i], b[j], acc[i][j]);
  }
}

// ---- K2: per-chunk KV sums ----
__global__ __launch_bounds__(256) void k2_kvchunk(const float* __restrict__ sk,
                                                  const float* __restrict__ vb,
                                                  float* __restrict__ kvc) {
  __shared__ float As[16][68];
  __shared__ float Bs[16][68];
  int tid = threadIdx.x;
  int c = blockIdx.x;
  int d0 = (blockIdx.y >> 2) * 64;
  int e0 = (blockIdx.y & 3) * 64;
  int row0 = c * CHUNK;
  float acc[4][4] = {};
  for (int kk = 0; kk < CHUNK; kk += 16) {
    load_KN(As, sk, DMEM, row0 + kk, d0, tid);
    load_KN(Bs, vb, DMEM, row0 + kk, e0, tid);
    __syncthreads();
    micro_mm(As, Bs, tid, acc);
    __syncthreads();
  }
  int ty = tid >> 4, tx = tid & 15;
#pragma unroll
  for (int i = 0; i < 4; ++i)
#pragma unroll
    for (int j = 0; j < 4; ++j)
      kvc[(size_t)c * DMEM * DMEM + (size_t)(d0 + ty * 4 + i) * DMEM + e0 + tx * 4 + j] =
          acc[i][j];
}

// ---- K2b: per-chunk column sums of sigma_k ----
__global__ void k2b_ksum(const float* __restrict__ sk, float* __restrict__ ksc) {
  int c = blockIdx.x;
  int d = threadIdx.x;
  float s = 0.f;
  for (int i = 0; i < CHUNK; ++i) s += sk[(size_t)(c * CHUNK + i) * DMEM + d];
  ksc[c * DMEM + d] = s;
}

// ---- K3: exclusive chunk prefix + memnorm flag ----
__global__ void k3_prefix(float* __restrict__ kvc, const float* __restrict__ ksc,
                          float* __restrict__ ksp, const float* __restrict__ mnorm,
                          float* __restrict__ flag) {
  int b = blockIdx.x;
  if (b < 1024) {
    int batch = b >> 8;
    int idx = (b & 255) * 256 + threadIdx.x;
    float run = 0.f;
    for (int c = 0; c < NCH; ++c) {
      size_t off = (size_t)(batch * NCH + c) * DMEM * DMEM + idx;
      float t = kvc[off];
      kvc[off] = run;
      run += t;
    }
  } else if (b < 1028) {
    int batch = b - 1024;
    int d = threadIdx.x;
    float run = 0.f;
    for (int c = 0; c < NCH; ++c) {
      int off = (batch * NCH + c) * DMEM + d;
      float t = ksc[off];
      ksp[off] = run;
      run += t;
    }
  } else {
    __shared__ float red[256];
    red[threadIdx.x] = mnorm[threadIdx.x];
    __syncthreads();
    for (int s = 128; s > 0; s >>= 1) {
      if (threadIdx.x < s) red[threadIdx.x] += red[threadIdx.x + s];
      __syncthreads();
    }
    if (threadIdx.x == 0) *flag = (red[0] < EPSF) ? 0.f : 1.f;
  }
}

// ---- K4a: intra-chunk causal scores ----
__global__ __launch_bounds__(256) void k4a_scores(const float* __restrict__ sq,
                                                  const float* __restrict__ sk,
                                                  float* __restrict__ sc) {
  __shared__ float As[16][68];
  __shared__ float Bs[16][68];
  int tid = threadIdx.x;
  int c = blockIdx.x;
  int i0 = (blockIdx.y >> 1) * 64;
  int j0 = (blockIdx.y & 1) * 64;
  float acc[4][4] = {};
  for (int k0 = 0; k0 < DMEM; k0 += 16) {
    load_MK(As, sq, DMEM, c * CHUNK + i0, k0, tid);
    load_MK(Bs, sk, DMEM, c * CHUNK + j0, k0, tid);
    __syncthreads();
    micro_mm(As, Bs, tid, acc);
    __syncthreads();
  }
  int ty = tid >> 4, tx = tid & 15;
#pragma unroll
  for (int i = 0; i < 4; ++i)
#pragma unroll
    for (int j = 0; j < 4; ++j) {
      int ii = i0 + ty * 4 + i;
      int jj = j0 + tx * 4 + j;
      sc[(size_t)c * CHUNK * CHUNK + (size_t)ii * CHUNK + jj] = (jj <= ii) ? acc[i][j] : 0.f;
    }
}

// ---- K4p: per-row scalars ----
__global__ __launch_bounds__(256) void k4p_rows(const float* __restrict__ sc,
                                                const float* __restrict__ sq,
                                                const float* __restrict__ sk,
                                                const float* __restrict__ ksp,
                                                const float* __restrict__ mnorm,
                                                float* __restrict__ den, float* __restrict__ qn,
                                                float* __restrict__ kn) {
  int wave = threadIdx.x >> 6;
  int lane = threadIdx.x & 63;
  int m = blockIdx.x * 4 + wave;
  int c = m / CHUNK;
  int i = m % CHUNK;
  float s_sc = 0.f, s_d2 = 0.f, s_qn = 0.f, s_kn = 0.f;
  for (int j = lane; j < CHUNK; j += 64)
    s_sc += sc[(size_t)c * CHUNK * CHUNK + (size_t)i * CHUNK + j];
  for (int d = lane; d < DMEM; d += 64) {
    float q = sq[(size_t)m * DMEM + d];
    float k = sk[(size_t)m * DMEM + d];
    s_d2 += q * ksp[c * DMEM + d];
    s_qn += q * mnorm[d];
    s_kn += k * mnorm[d];
  }
#pragma unroll
  for (int off = 32; off > 0; off >>= 1) {
    s_sc += __shfl_down(s_sc, off);
    s_d2 += __shfl_down(s_d2, off);
    s_qn += __shfl_down(s_qn, off);
    s_kn += __shfl_down(s_kn, off);
  }
  if (lane == 0) {
    den[m] = s_sc + s_d2;
    qn[m] = s_qn;
    kn[m] = s_kn;
  }
}

// ---- K4b: local output ----
__global__ __launch_bounds__(256) void k4b_local(const float* __restrict__ sc,
                                                 const float* __restrict__ sq,
                                                 const float* __restrict__ vb,
                                                 const float* __restrict__ kvp,
                                                 const float* __restrict__ den,
                                                 float* __restrict__ loc) {
  __shared__ float As[16][68];
  __shared__ float Bs[16][68];
  int tid = threadIdx.x;
  int c = blockIdx.x;
  int i0 = (blockIdx.y >> 2) * 64;
  int e0 = (blockIdx.y & 3) * 64;
  float acc[4][4] = {};
  for (int k0 = 0; k0 < CHUNK; k0 += 16) {
    load_MK(As, sc + (size_t)c * CHUNK * CHUNK, CHUNK, i0, k0, tid);
    load_KN(Bs, vb, DMEM, c * CHUNK + k0, e0, tid);
    __syncthreads();
    micro_mm(As, Bs, tid, acc);
    __syncthreads();
  }
  for (int k0 = 0; k0 < DMEM; k0 += 16) {
    load_MK(As, sq, DMEM, c * CHUNK + i0, k0, tid);
    load_KN(Bs, kvp + (size_t)c * DMEM * DMEM, DMEM, k0, e0, tid);
    __syncthreads();
    micro_mm(As, Bs, tid, acc);
    __syncthreads();
  }
  int ty = tid >> 4, tx = tid & 15;
#pragma unroll
  for (int i = 0; i < 4; ++i)
#pragma unroll
    for (int j = 0; j < 4; ++j) {
      int m = c * CHUNK + i0 + ty * 4 + i;
      int e = e0 + tx * 4 + j;
      loc[(size_t)m * DMEM + e] = acc[i][j] / fmaxf(den[m], EPSF);
    }
}

// ---- K5: memory retrieval + gate combine -> bf16 comb ----
__global__ __launch_bounds__(256) void k5_combine(const float* __restrict__ sq,
                                                  const float* __restrict__ mem,
                                                  const float* __restrict__ qn,
                                                  const float* __restrict__ gate,
                                                  const float* __restrict__ flag,
                                                  const float* __restrict__ loc,
                                                  __bf16* __restrict__ combb) {
  __shared__ float As[16][68];
  __shared__ float Bs[16][68];
  int tid = threadIdx.x;
  int m0 = blockIdx.x * 64;
  int n0 = blockIdx.y * 64;
  float acc[4][4] = {};
  for (int k0 = 0; k0 < DMEM; k0 += 16) {
    load_MK(As, sq, DMEM, m0, k0, tid);
    load_KN(Bs, mem, DMEM, k0, n0, tid);
    __syncthreads();
    micro_mm(As, Bs, tid, acc);
    __syncthreads();
  }
  float g = 1.f / (1.f + __expf(-gate[0]));
  float fl = *flag;
  int ty = tid >> 4, tx = tid & 15;
#pragma unroll
  for (int i = 0; i < 4; ++i)
#pragma unroll
    for (int j = 0; j < 4; ++j) {
      int m = m0 + ty * 4 + i;
      int n = n0 + tx * 4 + j;
      size_t off = (size_t)m * DMEM + n;
      float mo = fl * acc[i][j] / fmaxf(qn[m], EPSF);
      combb[off] = (__bf16)(g * mo + (1.f - g) * loc[off]);
    }
}

// ---- K7a: delta_v ----
__global__ __launch_bounds__(256) void k7a_delta(const float* __restrict__ sk,
                                                 const float* __restrict__ mem,
                                                 const float* __restrict__ kn,
                                                 const float* __restrict__ vb,
                                                 float* __restrict__ dv) {
  __shared__ float As[16][68];
  __shared__ float Bs[16][68];
  int tid = threadIdx.x;
  int m0 = blockIdx.x * 64;
  int n0 = blockIdx.y * 64;
  float acc[4][4] = {};
  for (int k0 = 0; k0 < DMEM; k0 += 16) {
    load_MK(As, sk, DMEM, m0, k0, tid);
    load_KN(Bs, mem, DMEM, k0, n0, tid);
    __syncthreads();
    micro_mm(As, Bs, tid, acc);
    __syncthreads();
  }
  int ty = tid >> 4, tx = tid & 15;
#pragma unroll
  for (int i = 0; i < 4; ++i)
#pragma unroll
    for (int j = 0; j < 4; ++j) {
      int m = m0 + ty * 4 + i;
      int n = n0 + tx * 4 + j;
      size_t off = (size_t)m * DMEM + n;
      dv[off] = vb[off] - acc[i][j] / fmaxf(kn[m], EPSF);
    }
}

// ---- K7init: seed new_memory region ----
__global__ void k7init(const float* __restrict__ mem, float* __restrict__ out) {
  int i = blockIdx.x * 256 + threadIdx.x;
  if (i < DMEM * DMEM) out[(size_t)MTOT * HIDDEN + i] = mem[i];
}

// ---- K7b: memory_update split-K ----
__global__ __launch_bounds__(256) void k7b_update(const float* __restrict__ sk,
                                                  const float* __restrict__ dv,
                                                  float* __restrict__ out) {
  __shared__ float As[16][68];
  __shared__ float Bs[16][68];
  int tid = threadIdx.x;
  int kseg = blockIdx.x;
  int d0 = (blockIdx.y >> 2) * 64;
  int e0 = (blockIdx.y & 3) * 64;
  int row0 = kseg * 256;
  float acc[4][4] = {};
  for (int kk = 0; kk < 256; kk += 16) {
    load_KN(As, sk, DMEM, row0 + kk, d0, tid);
    load_KN(Bs, dv, DMEM, row0 + kk, e0, tid);
    __syncthreads();
    micro_mm(As, Bs, tid, acc);
    __syncthreads();
  }
  int ty = tid >> 4, tx = tid & 15;
  float* base = out + (size_t)MTOT * HIDDEN;
#pragma unroll
  for (int i = 0; i < 4; ++i)
#pragma unroll
    for (int j = 0; j < 4; ++j)
      atomicAdd(&base[(size_t)(d0 + ty * 4 + i) * DMEM + e0 + tx * 4 + j],
                acc[i][j] * (1.f / (float)MTOT));
}

// ---- K7c: new_memory_norm ----
__global__ void k7c_norm(const float* __restrict__ ksc, const float* __restrict__ mnorm,
                         float* __restrict__ out) {
  int d = threadIdx.x;
  float s = 0.f;
  for (int c = 0; c < NCHT; ++c) s += ksc[c * DMEM + d];
  out[(size_t)MTOT * HIDDEN + DMEM * DMEM + d] = mnorm[d] + s * (1.f / (float)BATCH);
}

extern "C" void kernel_launch(void* const* d_in, const int* in_sizes, int n_in,
                              void* d_out, int out_size, void* d_ws, size_t ws_size,
                              hipStream_t stream) {
  const float* hs = (const float*)d_in[0];
  const float* wq = (const float*)d_in[1];
  const float* wk = (const float*)d_in[2];
  const float* wv = (const float*)d_in[3];
  const float* wo = (const float*)d_in[4];
  const float* gate = (const float*)d_in[5];
  const float* mem = (const float*)d_in[6];
  const float* mnorm = (const float*)d_in[7];
  float* out = (float*)d_out;
  float* ws = (float*)d_ws;

  // fp32 region
  float* sq = ws;                                    // 1048576
  float* sk = sq + (size_t)MTOT * DMEM;              // 1048576
  float* vb = sk + (size_t)MTOT * DMEM;              // 1048576
  float* kvc = vb + (size_t)MTOT * DMEM;             // 2097152
  float* ksc = kvc + (size_t)NCHT * DMEM * DMEM;     // 8192
  float* ksp = ksc + NCHT * DMEM;                    // 8192
  float* scor = ksp + NCHT * DMEM;                   // 524288
  float* den = scor + (size_t)NCHT * CHUNK * CHUNK;  // 4096
  float* qn = den + MTOT;
  float* kn = qn + MTOT;
  float* loc = kn + MTOT;           // 1048576
  float* flag = loc + (size_t)MTOT * DMEM;  // 4 floats (alignment pad)
  // bf16 region (16B-aligned: offset is multiple of 4 floats)
  __bf16* hsb = (__bf16*)(flag + 4);                  // 4194304
  __bf16* wqkvb = hsb + (size_t)MTOT * HIDDEN;        // 786432
  __bf16* wob = wqkvb + (size_t)3 * DMEM * HIDDEN;    // 262144
  __bf16* combb = wob + (size_t)HIDDEN * DMEM;        // 1048576
  float* dv = sq;  // alias: sigma_q dead after k5

  kcast_hs<<<dim3(4096), 256, 0, stream>>>(hs, hsb);
  kcast_w<<<dim3(256, 4), 256, 0, stream>>>(wq, wk, wv, wo, wqkvb, wob);
  k1_qkv_mfma<<<dim3(64, 6), 256, 0, stream>>>(hsb, wqkvb, sq, sk, vb);
  k2_kvchunk<<<dim3(NCHT, 16), 256, 0, stream>>>(sk, vb, kvc);
  k2b_ksum<<<dim3(NCHT), 256, 0, stream>>>(sk, ksc);
  k3_prefix<<<dim3(1029), 256, 0, stream>>>(kvc, ksc, ksp, mnorm, flag);
  k4a_scores<<<dim3(NCHT, 4), 256, 0, stream>>>(sq, sk, scor);
  k4p_rows<<<dim3(MTOT / 4), 256, 0, stream>>>(scor, sq, sk, ksp, mnorm, den, qn, kn);
  k4b_local<<<dim3(NCHT, 8), 256, 0, stream>>>(scor, sq, vb, kvc, den, loc);
  k5_combine<<<dim3(MTOT / 64, DMEM / 64), 256, 0, stream>>>(sq, mem, qn, gate, flag, loc, combb);
  k6_out_mfma<<<dim3(64, 8), 256, 0, stream>>>(combb, wob, out);
  k7a_delta<<<dim3(MTOT / 64, DMEM / 64), 256, 0, stream>>>(sk, mem, kn, vb, dv);
  k7init<<<dim3(DMEM * DMEM / 256), 256, 0, stream>>>(mem, out);
  k7b_update<<<dim3(16, 16), 256, 0, stream>>>(sk, dv, out);
  k7c_norm<<<dim3(1), 256, 0, stream>>>(ksc, mnorm, out);
}

// Round 3
// 179.822 us; speedup vs baseline: 2.0349x; 1.4568x over previous
//
#include <hip/hip_runtime.h>

// InfiniAttention — chunked linear attention. Round 3: ALL GEMMs on bf16 MFMA
// (16x16x32, 64x128 tiles, global_load_lds width-16 staging). k5 fused into k4b.

#define HIDDEN 1024
#define DMEM 256
#define BATCH 4
#define SEQ 1024
#define MTOT (BATCH * SEQ)      // 4096
#define CHUNK 128
#define NCH (SEQ / CHUNK)       // 8
#define NCHT (BATCH * NCH)      // 32
#define EPSF 1e-6f

typedef __bf16 bf16x8 __attribute__((ext_vector_type(8)));
typedef __bf16 bf16x4 __attribute__((ext_vector_type(4)));
typedef float f32x4 __attribute__((ext_vector_type(4)));

#define GL_LDS(g, l)                                                                   \
  __builtin_amdgcn_global_load_lds((const __attribute__((address_space(1))) void*)(g), \
                                   (__attribute__((address_space(3))) void*)(l), 16, 0, 0)

__device__ __forceinline__ float elu1(float x) { return x > 0.f ? x + 1.f : __expf(x); }

// ---------------- casts ----------------
__global__ void kcast_hs(const float* __restrict__ src, __bf16* __restrict__ dst) {
  int i = blockIdx.x * 256 + threadIdx.x;
  float4 f = reinterpret_cast<const float4*>(src)[i];
  bf16x4 h = {(__bf16)f.x, (__bf16)f.y, (__bf16)f.z, (__bf16)f.w};
  reinterpret_cast<bf16x4*>(dst)[i] = h;
}

__global__ void kcast_w(const float* __restrict__ wq, const float* __restrict__ wk,
                        const float* __restrict__ wv, const float* __restrict__ wo,
                        __bf16* __restrict__ wqkvb, __bf16* __restrict__ wob) {
  int y = blockIdx.y;
  const float* src = (y == 0) ? wq : (y == 1) ? wk : (y == 2) ? wv : wo;
  __bf16* dst = (y < 3) ? wqkvb + (size_t)y * (DMEM * HIDDEN) : wob;
  int i = blockIdx.x * 256 + threadIdx.x;
  float4 f = reinterpret_cast<const float4*>(src)[i];
  bf16x4 h = {(__bf16)f.x, (__bf16)f.y, (__bf16)f.z, (__bf16)f.w};
  reinterpret_cast<bf16x4*>(dst)[i] = h;
}

// memT[n][d] = mem[d][n], bf16. 64x64 LDS tiles, grid(4,4).
__global__ void kcast_memT(const float* __restrict__ mem, __bf16* __restrict__ memT) {
  __shared__ float s[64][65];
  int tid = threadIdx.x;
  int r0 = tid >> 6, col = tid & 63;
  int bx = blockIdx.x, by = blockIdx.y;
#pragma unroll
  for (int it = 0; it < 16; ++it) {
    int row = it * 4 + r0;
    s[row][col] = mem[(size_t)(by * 64 + row) * DMEM + bx * 64 + col];
  }
  __syncthreads();
#pragma unroll
  for (int it = 0; it < 16; ++it) {
    int row = it * 4 + r0;
    memT[(size_t)(bx * 64 + row) * DMEM + by * 64 + col] = (__bf16)s[col][row];
  }
}

// ---------------- K1: fused QKV projection, bf16 MFMA ----------------
__global__ __launch_bounds__(256) void k1_qkv_mfma(
    const __bf16* __restrict__ X, const __bf16* __restrict__ W, float* __restrict__ sq,
    float* __restrict__ sk, float* __restrict__ vb, __bf16* __restrict__ sqb,
    __bf16* __restrict__ skb, __bf16* __restrict__ skT, __bf16* __restrict__ vT) {
  __shared__ __bf16 As[64 * 32];
  __shared__ __bf16 Bs[128 * 32];
  int tid = threadIdx.x;
  int lane = tid & 63, wave = tid >> 6;
  int m0 = blockIdx.x * 64;
  int by = blockIdx.y;  // 0..5
  const __bf16* Wb = W + (size_t)by * 128 * HIDDEN;

  int arow = tid >> 2, acol = (tid & 3) << 3;
  const __bf16* aptr = X + (size_t)(m0 + arow) * HIDDEN + acol;
  const __bf16* bptr = Wb + (size_t)arow * HIDDEN + acol;
  __bf16* alds = As + wave * 512;
  __bf16* blds = Bs + wave * 512;

  int wr = wave >> 1, wc = wave & 1;
  int quad = lane >> 4, l16 = lane & 15;
  f32x4 acc[2][4] = {};

  for (int k0 = 0; k0 < HIDDEN; k0 += 32) {
    GL_LDS(aptr + k0, alds);
    GL_LDS(bptr + k0, blds);
    GL_LDS(bptr + 64 * HIDDEN + k0, blds + 2048);
    __syncthreads();
    bf16x8 aF[2], bF[4];
#pragma unroll
    for (int i = 0; i < 2; ++i)
      aF[i] = *reinterpret_cast<const bf16x8*>(As + (wr * 32 + i * 16 + l16) * 32 + quad * 8);
#pragma unroll
    for (int j = 0; j < 4; ++j)
      bF[j] = *reinterpret_cast<const bf16x8*>(Bs + (wc * 64 + j * 16 + l16) * 32 + quad * 8);
#pragma unroll
    for (int i = 0; i < 2; ++i)
#pragma unroll
      for (int j = 0; j < 4; ++j)
        acc[i][j] = __builtin_amdgcn_mfma_f32_16x16x32_bf16(aF[i], bF[j], acc[i][j], 0, 0, 0);
    __syncthreads();
  }

  int wsel = by >> 1;
  int nbase = (by & 1) * 128 + wc * 64;
#pragma unroll
  for (int i = 0; i < 2; ++i)
#pragma unroll
    for (int j = 0; j < 4; ++j) {
      int mb = m0 + wr * 32 + i * 16 + quad * 4;
      int n = nbase + j * 16 + l16;
      float vals[4];
#pragma unroll
      for (int r = 0; r < 4; ++r) {
        float v = acc[i][j][r];
        if (wsel < 2) v = elu1(v);
        vals[r] = v;
      }
      if (wsel == 0) {
#pragma unroll
        for (int r = 0; r < 4; ++r) {
          sq[(size_t)(mb + r) * DMEM + n] = vals[r];
          sqb[(size_t)(mb + r) * DMEM + n] = (__bf16)vals[r];
        }
      } else if (wsel == 1) {
        bf16x4 t;
#pragma unroll
        for (int r = 0; r < 4; ++r) {
          sk[(size_t)(mb + r) * DMEM + n] = vals[r];
          skb[(size_t)(mb + r) * DMEM + n] = (__bf16)vals[r];
          t[r] = (__bf16)vals[r];
        }
        *reinterpret_cast<bf16x4*>(skT + (size_t)n * MTOT + mb) = t;
      } else {
        bf16x4 t;
#pragma unroll
        for (int r = 0; r < 4; ++r) {
          vb[(size_t)(mb + r) * DMEM + n] = vals[r];
          t[r] = (__bf16)vals[r];
        }
        *reinterpret_cast<bf16x4*>(vT + (size_t)n * MTOT + mb) = t;
      }
    }
}

// ---------------- K2: chunk KV sums (transposed out). kvcT[c][e][d] ----------------
// C[e][d] = sum_{s in chunk} vT[e,s]*skT[d,s]. grid (NCHT, 8): e0=(by>>1)*64, d0=(by&1)*128.
__global__ __launch_bounds__(256) void k2_mfma(const __bf16* __restrict__ vT,
                                               const __bf16* __restrict__ skT,
                                               float* __restrict__ kvcT) {
  __shared__ __bf16 As[64 * 32];
  __shared__ __bf16 Bs[128 * 32];
  int tid = threadIdx.x;
  int lane = tid & 63, wave = tid >> 6;
  int c = blockIdx.x;
  int e0 = (blockIdx.y >> 1) * 64, d0 = (blockIdx.y & 1) * 128;
  int arow = tid >> 2, acol = (tid & 3) << 3;
  const __bf16* aptr = vT + (size_t)(e0 + arow) * MTOT + c * CHUNK + acol;
  const __bf16* bptr = skT + (size_t)(d0 + arow) * MTOT + c * CHUNK + acol;
  __bf16* alds = As + wave * 512;
  __bf16* blds = Bs + wave * 512;
  int wr = wave >> 1, wc = wave & 1, quad = lane >> 4, l16 = lane & 15;
  f32x4 acc[2][4] = {};
  for (int k0 = 0; k0 < CHUNK; k0 += 32) {
    GL_LDS(aptr + k0, alds);
    GL_LDS(bptr + k0, blds);
    GL_LDS(bptr + (size_t)64 * MTOT + k0, blds + 2048);
    __syncthreads();
    bf16x8 aF[2], bF[4];
#pragma unroll
    for (int i = 0; i < 2; ++i)
      aF[i] = *reinterpret_cast<const bf16x8*>(As + (wr * 32 + i * 16 + l16) * 32 + quad * 8);
#pragma unroll
    for (int j = 0; j < 4; ++j)
      bF[j] = *reinterpret_cast<const bf16x8*>(Bs + (wc * 64 + j * 16 + l16) * 32 + quad * 8);
#pragma unroll
    for (int i = 0; i < 2; ++i)
#pragma unroll
      for (int j = 0; j < 4; ++j)
        acc[i][j] = __builtin_amdgcn_mfma_f32_16x16x32_bf16(aF[i], bF[j], acc[i][j], 0, 0, 0);
    __syncthreads();
  }
#pragma unroll
  for (int i = 0; i < 2; ++i)
#pragma unroll
    for (int j = 0; j < 4; ++j)
#pragma unroll
      for (int r = 0; r < 4; ++r) {
        int e = e0 + wr * 32 + i * 16 + quad * 4 + r;
        int d = d0 + wc * 64 + j * 16 + l16;
        kvcT[(size_t)c * DMEM * DMEM + (size_t)e * DMEM + d] = acc[i][j][r];
      }
}

// ---- K2b: per-chunk column sums of sigma_k (fp32) ----
__global__ void k2b_ksum(const float* __restrict__ sk, float* __restrict__ ksc) {
  int c = blockIdx.x;
  int d = threadIdx.x;
  float s = 0.f;
  for (int i = 0; i < CHUNK; ++i) s += sk[(size_t)(c * CHUNK + i) * DMEM + d];
  ksc[c * DMEM + d] = s;
}

// ---- K3: exclusive chunk prefix (kvcT fp32 -> kvpT bf16; ksc -> ksp) + flag ----
__global__ void k3_prefix(const float* __restrict__ kvcT, __bf16* __restrict__ kvpT,
                          const float* __restrict__ ksc, float* __restrict__ ksp,
                          const float* __restrict__ mnorm, float* __restrict__ flag) {
  int b = blockIdx.x;
  if (b < 1024) {
    int batch = b >> 8;
    int idx = (b & 255) * 256 + threadIdx.x;
    float run = 0.f;
    for (int c = 0; c < NCH; ++c) {
      size_t off = (size_t)(batch * NCH + c) * DMEM * DMEM + idx;
      kvpT[off] = (__bf16)run;
      run += kvcT[off];
    }
  } else if (b < 1028) {
    int batch = b - 1024;
    int d = threadIdx.x;
    float run = 0.f;
    for (int c = 0; c < NCH; ++c) {
      int off = (batch * NCH + c) * DMEM + d;
      ksp[off] = run;
      run += ksc[off];
    }
  } else {
    __shared__ float red[256];
    red[threadIdx.x] = mnorm[threadIdx.x];
    __syncthreads();
    for (int s = 128; s > 0; s >>= 1) {
      if (threadIdx.x < s) red[threadIdx.x] += red[threadIdx.x + s];
      __syncthreads();
    }
    if (threadIdx.x == 0) *flag = (red[0] < EPSF) ? 0.f : 1.f;
  }
}

// ---- K4a: intra-chunk causal scores -> bf16. grid (NCHT, 2): i0=by*64. ----
__global__ __launch_bounds__(256) void k4a_mfma(const __bf16* __restrict__ sqb,
                                                const __bf16* __restrict__ skb,
                                                __bf16* __restrict__ scb) {
  __shared__ __bf16 As[64 * 32];
  __shared__ __bf16 Bs[128 * 32];
  int tid = threadIdx.x;
  int lane = tid & 63, wave = tid >> 6;
  int c = blockIdx.x;
  int i0 = blockIdx.y * 64;
  int arow = tid >> 2, acol = (tid & 3) << 3;
  const __bf16* aptr = sqb + (size_t)(c * CHUNK + i0 + arow) * DMEM + acol;
  const __bf16* bptr = skb + (size_t)(c * CHUNK + arow) * DMEM + acol;
  __bf16* alds = As + wave * 512;
  __bf16* blds = Bs + wave * 512;
  int wr = wave >> 1, wc = wave & 1, quad = lane >> 4, l16 = lane & 15;
  f32x4 acc[2][4] = {};
  for (int k0 = 0; k0 < DMEM; k0 += 32) {
    GL_LDS(aptr + k0, alds);
    GL_LDS(bptr + k0, blds);
    GL_LDS(bptr + (size_t)64 * DMEM + k0, blds + 2048);
    __syncthreads();
    bf16x8 aF[2], bF[4];
#pragma unroll
    for (int i = 0; i < 2; ++i)
      aF[i] = *reinterpret_cast<const bf16x8*>(As + (wr * 32 + i * 16 + l16) * 32 + quad * 8);
#pragma unroll
    for (int j = 0; j < 4; ++j)
      bF[j] = *reinterpret_cast<const bf16x8*>(Bs + (wc * 64 + j * 16 + l16) * 32 + quad * 8);
#pragma unroll
    for (int i = 0; i < 2; ++i)
#pragma unroll
      for (int j = 0; j < 4; ++j)
        acc[i][j] = __builtin_amdgcn_mfma_f32_16x16x32_bf16(aF[i], bF[j], acc[i][j], 0, 0, 0);
    __syncthreads();
  }
#pragma unroll
  for (int i = 0; i < 2; ++i)
#pragma unroll
    for (int j = 0; j < 4; ++j)
#pragma unroll
      for (int r = 0; r < 4; ++r) {
        int ii = i0 + wr * 32 + i * 16 + quad * 4 + r;
        int jj = wc * 64 + j * 16 + l16;
        scb[(size_t)c * CHUNK * CHUNK + (size_t)ii * CHUNK + jj] =
            (jj <= ii) ? (__bf16)acc[i][j][r] : (__bf16)0.f;
      }
}

// ---- K4p: per-row scalars (reads bf16 scores) ----
__global__ __launch_bounds__(256) void k4p_rows(const __bf16* __restrict__ scb,
                                                const float* __restrict__ sq,
                                                const float* __restrict__ sk,
                                                const float* __restrict__ ksp,
                                                const float* __restrict__ mnorm,
                                                float* __restrict__ den, float* __restrict__ qn,
                                                float* __restrict__ kn) {
  int wave = threadIdx.x >> 6;
  int lane = threadIdx.x & 63;
  int m = blockIdx.x * 4 + wave;
  int c = m / CHUNK;
  int i = m % CHUNK;
  float s_sc = 0.f, s_d2 = 0.f, s_qn = 0.f, s_kn = 0.f;
  for (int j = lane; j < CHUNK; j += 64)
    s_sc += (float)scb[(size_t)c * CHUNK * CHUNK + (size_t)i * CHUNK + j];
  for (int d = lane; d < DMEM; d += 64) {
    float q = sq[(size_t)m * DMEM + d];
    float k = sk[(size_t)m * DMEM + d];
    s_d2 += q * ksp[c * DMEM + d];
    s_qn += q * mnorm[d];
    s_kn += k * mnorm[d];
  }
#pragma unroll
  for (int off = 32; off > 0; off >>= 1) {
    s_sc += __shfl_down(s_sc, off);
    s_d2 += __shfl_down(s_d2, off);
    s_qn += __shfl_down(s_qn, off);
    s_kn += __shfl_down(s_kn, off);
  }
  if (lane == 0) {
    den[m] = s_sc + s_d2;
    qn[m] = s_qn;
    kn[m] = s_kn;
  }
}

// ---- K4b (fused with K5): local output + retrieval + gate combine -> combb bf16 ----
// grid (NCHT, 4): i0=(by>>1)*64, e0=(by&1)*128.
__global__ __launch_bounds__(256) void k4b_fused(
    const __bf16* __restrict__ scb, const __bf16* __restrict__ sqb,
    const __bf16* __restrict__ vT, const __bf16* __restrict__ kvpT,
    const __bf16* __restrict__ memT, const float* __restrict__ den,
    const float* __restrict__ qn, const float* __restrict__ gate,
    const float* __restrict__ flag, __bf16* __restrict__ combb) {
  __shared__ __bf16 As[64 * 32];
  __shared__ __bf16 B1s[128 * 32];
  __shared__ __bf16 B2s[128 * 32];
  int tid = threadIdx.x;
  int lane = tid & 63, wave = tid >> 6;
  int c = blockIdx.x;
  int i0 = (blockIdx.y >> 1) * 64, e0 = (blockIdx.y & 1) * 128;
  int arow = tid >> 2, acol = (tid & 3) << 3;
  __bf16* alds = As + wave * 512;
  __bf16* b1lds = B1s + wave * 512;
  __bf16* b2lds = B2s + wave * 512;
  int wr = wave >> 1, wc = wave & 1, quad = lane >> 4, l16 = lane & 15;
  f32x4 acc_loc[2][4] = {};
  f32x4 acc_mem[2][4] = {};

  // phase 1: intra-chunk scores @ v. A=scb rows i (ld CHUNK), B=vT rows e (ld MTOT).
  {
    const __bf16* aptr = scb + (size_t)c * CHUNK * CHUNK + (size_t)(i0 + arow) * CHUNK + acol;
    const __bf16* bptr = vT + (size_t)(e0 + arow) * MTOT + c * CHUNK + acol;
    for (int k0 = 0; k0 < CHUNK; k0 += 32) {
      GL_LDS(aptr + k0, alds);
      GL_LDS(bptr + k0, b1lds);
      GL_LDS(bptr + (size_t)64 * MTOT + k0, b1lds + 2048);
      __syncthreads();
      bf16x8 aF[2], bF[4];
#pragma unroll
      for (int i = 0; i < 2; ++i)
        aF[i] = *reinterpret_cast<const bf16x8*>(As + (wr * 32 + i * 16 + l16) * 32 + quad * 8);
#pragma unroll
      for (int j = 0; j < 4; ++j)
        bF[j] = *reinterpret_cast<const bf16x8*>(B1s + (wc * 64 + j * 16 + l16) * 32 + quad * 8);
#pragma unroll
      for (int i = 0; i < 2; ++i)
#pragma unroll
        for (int j = 0; j < 4; ++j)
          acc_loc[i][j] =
              __builtin_amdgcn_mfma_f32_16x16x32_bf16(aF[i], bF[j], acc_loc[i][j], 0, 0, 0);
      __syncthreads();
    }
  }
  // phase 2: A=sqb rows m. B1=kvpT[c] rows e, B2=memT rows e (both ld DMEM).
  {
    const __bf16* aptr = sqb + (size_t)(c * CHUNK + i0 + arow) * DMEM + acol;
    const __bf16* b1ptr = kvpT + (size_t)c * DMEM * DMEM + (size_t)(e0 + arow) * DMEM + acol;
    const __bf16* b2ptr = memT + (size_t)(e0 + arow) * DMEM + acol;
    for (int k0 = 0; k0 < DMEM; k0 += 32) {
      GL_LDS(aptr + k0, alds);
      GL_LDS(b1ptr + k0, b1lds);
      GL_LDS(b1ptr + (size_t)64 * DMEM + k0, b1lds + 2048);
      GL_LDS(b2ptr + k0, b2lds);
      GL_LDS(b2ptr + (size_t)64 * DMEM + k0, b2lds + 2048);
      __syncthreads();
      bf16x8 aF[2], b1F[4], b2F[4];
#pragma unroll
      for (int i = 0; i < 2; ++i)
        aF[i] = *reinterpret_cast<const bf16x8*>(As + (wr * 32 + i * 16 + l16) * 32 + quad * 8);
#pragma unroll
      for (int j = 0; j < 4; ++j) {
        b1F[j] = *reinterpret_cast<const bf16x8*>(B1s + (wc * 64 + j * 16 + l16) * 32 + quad * 8);
        b2F[j] = *reinterpret_cast<const bf16x8*>(B2s + (wc * 64 + j * 16 + l16) * 32 + quad * 8);
      }
#pragma unroll
      for (int i = 0; i < 2; ++i)
#pragma unroll
        for (int j = 0; j < 4; ++j) {
          acc_loc[i][j] =
              __builtin_amdgcn_mfma_f32_16x16x32_bf16(aF[i], b1F[j], acc_loc[i][j], 0, 0, 0);
          acc_mem[i][j] =
              __builtin_amdgcn_mfma_f32_16x16x32_bf16(aF[i], b2F[j], acc_mem[i][j], 0, 0, 0);
        }
      __syncthreads();
    }
  }
  float g = 1.f / (1.f + __expf(-gate[0]));
  float fl = *flag;
#pragma unroll
  for (int i = 0; i < 2; ++i) {
    int mb = c * CHUNK + i0 + wr * 32 + i * 16 + quad * 4;
    float dn[4], qv[4];
#pragma unroll
    for (int r = 0; r < 4; ++r) {
      dn[r] = fmaxf(den[mb + r], EPSF);
      qv[r] = fmaxf(qn[mb + r], EPSF);
    }
#pragma unroll
    for (int j = 0; j < 4; ++j) {
      int e = e0 + wc * 64 + j * 16 + l16;
#pragma unroll
      for (int r = 0; r < 4; ++r) {
        float comb = g * fl * acc_mem[i][j][r] / qv[r] + (1.f - g) * acc_loc[i][j][r] / dn[r];
        combb[(size_t)(mb + r) * DMEM + e] = (__bf16)comb;
      }
    }
  }
}

// ---------------- K6: output projection, bf16 MFMA ----------------
__global__ __launch_bounds__(256) void k6_out_mfma(const __bf16* __restrict__ A,
                                                   const __bf16* __restrict__ B,
                                                   float* __restrict__ out) {
  __shared__ __bf16 As[64 * 32];
  __shared__ __bf16 Bs[128 * 32];
  int tid = threadIdx.x;
  int lane = tid & 63, wave = tid >> 6;
  int m0 = blockIdx.x * 64;
  int by = blockIdx.y;
  const __bf16* Bb = B + (size_t)by * 128 * DMEM;
  int arow = tid >> 2, acol = (tid & 3) << 3;
  const __bf16* aptr = A + (size_t)(m0 + arow) * DMEM + acol;
  const __bf16* bptr = Bb + (size_t)arow * DMEM + acol;
  __bf16* alds = As + wave * 512;
  __bf16* blds = Bs + wave * 512;
  int wr = wave >> 1, wc = wave & 1, quad = lane >> 4, l16 = lane & 15;
  f32x4 acc[2][4] = {};
  for (int k0 = 0; k0 < DMEM; k0 += 32) {
    GL_LDS(aptr + k0, alds);
    GL_LDS(bptr + k0, blds);
    GL_LDS(bptr + 64 * DMEM + k0, blds + 2048);
    __syncthreads();
    bf16x8 aF[2], bF[4];
#pragma unroll
    for (int i = 0; i < 2; ++i)
      aF[i] = *reinterpret_cast<const bf16x8*>(As + (wr * 32 + i * 16 + l16) * 32 + quad * 8);
#pragma unroll
    for (int j = 0; j < 4; ++j)
      bF[j] = *reinterpret_cast<const bf16x8*>(Bs + (wc * 64 + j * 16 + l16) * 32 + quad * 8);
#pragma unroll
    for (int i = 0; i < 2; ++i)
#pragma unroll
      for (int j = 0; j < 4; ++j)
        acc[i][j] = __builtin_amdgcn_mfma_f32_16x16x32_bf16(aF[i], bF[j], acc[i][j], 0, 0, 0);
    __syncthreads();
  }
#pragma unroll
  for (int i = 0; i < 2; ++i)
#pragma unroll
    for (int j = 0; j < 4; ++j)
#pragma unroll
      for (int r = 0; r < 4; ++r) {
        int m = m0 + wr * 32 + i * 16 + quad * 4 + r;
        int n = by * 128 + wc * 64 + j * 16 + l16;
        out[(size_t)m * HIDDEN + n] = acc[i][j][r];
      }
}

// ---- K7a: retrieved = skb@memT; dv = vb - ret/kn -> dvT bf16. grid (64,2). ----
__global__ __launch_bounds__(256) void k7a_mfma(const __bf16* __restrict__ skb,
                                                const __bf16* __restrict__ memT,
                                                const float* __restrict__ kn,
                                                const float* __restrict__ vb,
                                                __bf16* __restrict__ dvT) {
  __shared__ __bf16 As[64 * 32];
  __shared__ __bf16 Bs[128 * 32];
  int tid = threadIdx.x;
  int lane = tid & 63, wave = tid >> 6;
  int m0 = blockIdx.x * 64;
  int n0 = blockIdx.y * 128;
  int arow = tid >> 2, acol = (tid & 3) << 3;
  const __bf16* aptr = skb + (size_t)(m0 + arow) * DMEM + acol;
  const __bf16* bptr = memT + (size_t)(n0 + arow) * DMEM + acol;
  __bf16* alds = As + wave * 512;
  __bf16* blds = Bs + wave * 512;
  int wr = wave >> 1, wc = wave & 1, quad = lane >> 4, l16 = lane & 15;
  f32x4 acc[2][4] = {};
  for (int k0 = 0; k0 < DMEM; k0 += 32) {
    GL_LDS(aptr + k0, alds);
    GL_LDS(bptr + k0, blds);
    GL_LDS(bptr + (size_t)64 * DMEM + k0, blds + 2048);
    __syncthreads();
    bf16x8 aF[2], bF[4];
#pragma unroll
    for (int i = 0; i < 2; ++i)
      aF[i] = *reinterpret_cast<const bf16x8*>(As + (wr * 32 + i * 16 + l16) * 32 + quad * 8);
#pragma unroll
    for (int j = 0; j < 4; ++j)
      bF[j] = *reinterpret_cast<const bf16x8*>(Bs + (wc * 64 + j * 16 + l16) * 32 + quad * 8);
#pragma unroll
    for (int i = 0; i < 2; ++i)
#pragma unroll
      for (int j = 0; j < 4; ++j)
        acc[i][j] = __builtin_amdgcn_mfma_f32_16x16x32_bf16(aF[i], bF[j], acc[i][j], 0, 0, 0);
    __syncthreads();
  }
#pragma unroll
  for (int i = 0; i < 2; ++i) {
    int mb = m0 + wr * 32 + i * 16 + quad * 4;
    float kv[4];
#pragma unroll
    for (int r = 0; r < 4; ++r) kv[r] = fmaxf(kn[mb + r], EPSF);
#pragma unroll
    for (int j = 0; j < 4; ++j) {
      int n = n0 + wc * 64 + j * 16 + l16;
      bf16x4 t;
#pragma unroll
      for (int r = 0; r < 4; ++r)
        t[r] = (__bf16)(vb[(size_t)(mb + r) * DMEM + n] - acc[i][j][r] / kv[r]);
      *reinterpret_cast<bf16x4*>(dvT + (size_t)n * MTOT + mb) = t;
    }
  }
}

// ---- K7init: seed new_memory region ----
__global__ void k7init(const float* __restrict__ mem, float* __restrict__ out) {
  int i = blockIdx.x * 256 + threadIdx.x;
  if (i < DMEM * DMEM) out[(size_t)MTOT * HIDDEN + i] = mem[i];
}

// ---- K7b: memory_update split-K MFMA. grid (8, 8): kseg, d0=(by>>1)*64, e0=(by&1)*128. ----
__global__ __launch_bounds__(256) void k7b_mfma(const __bf16* __restrict__ skT,
                                                const __bf16* __restrict__ dvT,
                                                float* __restrict__ out) {
  __shared__ __bf16 As[64 * 32];
  __shared__ __bf16 Bs[128 * 32];
  int tid = threadIdx.x;
  int lane = tid & 63, wave = tid >> 6;
  int kbase = blockIdx.x * 512;
  int d0 = (blockIdx.y >> 1) * 64, e0 = (blockIdx.y & 1) * 128;
  int arow = tid >> 2, acol = (tid & 3) << 3;
  const __bf16* aptr = skT + (size_t)(d0 + arow) * MTOT + kbase + acol;
  const __bf16* bptr = dvT + (size_t)(e0 + arow) * MTOT + kbase + acol;
  __bf16* alds = As + wave * 512;
  __bf16* blds = Bs + wave * 512;
  int wr = wave >> 1, wc = wave & 1, quad = lane >> 4, l16 = lane & 15;
  f32x4 acc[2][4] = {};
  for (int k0 = 0; k0 < 512; k0 += 32) {
    GL_LDS(aptr + k0, alds);
    GL_LDS(bptr + k0, blds);
    GL_LDS(bptr + (size_t)64 * MTOT + k0, blds + 2048);
    __syncthreads();
    bf16x8 aF[2], bF[4];
#pragma unroll
    for (int i = 0; i < 2; ++i)
      aF[i] = *reinterpret_cast<const bf16x8*>(As + (wr * 32 + i * 16 + l16) * 32 + quad * 8);
#pragma unroll
    for (int j = 0; j < 4; ++j)
      bF[j] = *reinterpret_cast<const bf16x8*>(Bs + (wc * 64 + j * 16 + l16) * 32 + quad * 8);
#pragma unroll
    for (int i = 0; i < 2; ++i)
#pragma unroll
      for (int j = 0; j < 4; ++j)
        acc[i][j] = __builtin_amdgcn_mfma_f32_16x16x32_bf16(aF[i], bF[j], acc[i][j], 0, 0, 0);
    __syncthreads();
  }
  float* base = out + (size_t)MTOT * HIDDEN;
#pragma unroll
  for (int i = 0; i < 2; ++i)
#pragma unroll
    for (int j = 0; j < 4; ++j)
#pragma unroll
      for (int r = 0; r < 4; ++r) {
        int d = d0 + wr * 32 + i * 16 + quad * 4 + r;
        int e = e0 + wc * 64 + j * 16 + l16;
        atomicAdd(&base[(size_t)d * DMEM + e], acc[i][j][r] * (1.f / (float)MTOT));
      }
}

// ---- K7c: new_memory_norm ----
__global__ void k7c_norm(const float* __restrict__ ksc, const float* __restrict__ mnorm,
                         float* __restrict__ out) {
  int d = threadIdx.x;
  float s = 0.f;
  for (int c = 0; c < NCHT; ++c) s += ksc[c * DMEM + d];
  out[(size_t)MTOT * HIDDEN + DMEM * DMEM + d] = mnorm[d] + s * (1.f / (float)BATCH);
}

extern "C" void kernel_launch(void* const* d_in, const int* in_sizes, int n_in,
                              void* d_out, int out_size, void* d_ws, size_t ws_size,
                              hipStream_t stream) {
  const float* hs = (const float*)d_in[0];
  const float* wq = (const float*)d_in[1];
  const float* wk = (const float*)d_in[2];
  const float* wv = (const float*)d_in[3];
  const float* wo = (const float*)d_in[4];
  const float* gate = (const float*)d_in[5];
  const float* mem = (const float*)d_in[6];
  const float* mnorm = (const float*)d_in[7];
  float* out = (float*)d_out;
  float* ws = (float*)d_ws;

  // fp32 region
  float* sq = ws;                                   // 1048576
  float* sk = sq + (size_t)MTOT * DMEM;             // 1048576
  float* vb = sk + (size_t)MTOT * DMEM;             // 1048576
  float* kvcT = vb + (size_t)MTOT * DMEM;           // 2097152
  float* ksc = kvcT + (size_t)NCHT * DMEM * DMEM;   // 8192
  float* ksp = ksc + NCHT * DMEM;                   // 8192
  float* den = ksp + NCHT * DMEM;                   // 4096
  float* qn = den + MTOT;                           // 4096
  float* kn = qn + MTOT;                            // 4096
  float* flag = kn + MTOT;                          // 4 (pad)
  // bf16 region (16B aligned)
  __bf16* hsb = (__bf16*)(flag + 4);                // 4194304
  __bf16* wqkvb = hsb + (size_t)MTOT * HIDDEN;      // 786432
  __bf16* wob = wqkvb + (size_t)3 * DMEM * HIDDEN;  // 262144
  __bf16* memT = wob + (size_t)HIDDEN * DMEM;       // 65536
  __bf16* sqb = memT + (size_t)DMEM * DMEM;         // 1048576
  __bf16* skb = sqb + (size_t)MTOT * DMEM;          // 1048576
  __bf16* skT = skb + (size_t)MTOT * DMEM;          // 1048576
  __bf16* vT = skT + (size_t)MTOT * DMEM;           // 1048576
  __bf16* scb = vT + (size_t)MTOT * DMEM;           // 524288
  __bf16* kvpT = scb + (size_t)NCHT * CHUNK * CHUNK;  // 2097152
  __bf16* combb = kvpT + (size_t)NCHT * DMEM * DMEM;  // 1048576
  __bf16* dvT = combb + (size_t)MTOT * DMEM;          // 1048576

  kcast_hs<<<dim3(4096), 256, 0, stream>>>(hs, hsb);
  kcast_w<<<dim3(256, 4), 256, 0, stream>>>(wq, wk, wv, wo, wqkvb, wob);
  kcast_memT<<<dim3(4, 4), 256, 0, stream>>>(mem, memT);
  k1_qkv_mfma<<<dim3(64, 6), 256, 0, stream>>>(hsb, wqkvb, sq, sk, vb, sqb, skb, skT, vT);
  k2_mfma<<<dim3(NCHT, 8), 256, 0, stream>>>(vT, skT, kvcT);
  k2b_ksum<<<dim3(NCHT), 256, 0, stream>>>(sk, ksc);
  k3_prefix<<<dim3(1029), 256, 0, stream>>>(kvcT, kvpT, ksc, ksp, mnorm, flag);
  k4a_mfma<<<dim3(NCHT, 2), 256, 0, stream>>>(sqb, skb, scb);
  k4p_rows<<<dim3(MTOT / 4), 256, 0, stream>>>(scb, sq, sk, ksp, mnorm, den, qn, kn);
  k4b_fused<<<dim3(NCHT, 4), 256, 0, stream>>>(scb, sqb, vT, kvpT, memT, den, qn, gate, flag,
                                               combb);
  k6_out_mfma<<<dim3(64, 8), 256, 0, stream>>>(combb, wob, out);
  k7a_mfma<<<dim3(64, 2), 256, 0, stream>>>(skb, memT, kn, vb, dvT);
  k7init<<<dim3(DMEM * DMEM / 256), 256, 0, stream>>>(mem, out);
  k7b_mfma<<<dim3(8, 8), 256, 0, stream>>>(skT, dvT, out);
  k7c_norm<<<dim3(1), 256, 0, stream>>>(ksc, mnorm, out);
}

// Round 4
// 174.456 us; speedup vs baseline: 2.0975x; 1.0308x over previous
//
#include <hip/hip_runtime.h>

// InfiniAttention — chunked linear attention. Round 4: 128x128-tile MFMA for k1/k6/k7a,
// bf16-only intermediates (no fp32 sq/sk/vb), launches fused 16 -> 10.

#define HIDDEN 1024
#define DMEM 256
#define BATCH 4
#define SEQ 1024
#define MTOT (BATCH * SEQ)      // 4096
#define CHUNK 128
#define NCH (SEQ / CHUNK)       // 8
#define NCHT (BATCH * NCH)      // 32
#define EPSF 1e-6f

typedef __bf16 bf16x8 __attribute__((ext_vector_type(8)));
typedef __bf16 bf16x4 __attribute__((ext_vector_type(4)));
typedef float f32x4 __attribute__((ext_vector_type(4)));

#define GL_LDS(g, l)                                                                   \
  __builtin_amdgcn_global_load_lds((const __attribute__((address_space(1))) void*)(g), \
                                   (__attribute__((address_space(3))) void*)(l), 16, 0, 0)

__device__ __forceinline__ float elu1(float x) { return x > 0.f ? x + 1.f : __expf(x); }

// 128x128 tile K-loop. Requires in scope: As[128*32], Bs[128*32], wave, wr, wc, quad,
// l16, acc[4][4]. aptr/bptr already offset by (tid>>2) rows and (tid&3)*8 cols.
#define GEMM128_K(aptr, lda, bptr, ldb, KLEN)                                              \
  for (int k0 = 0; k0 < (KLEN); k0 += 32) {                                                \
    GL_LDS((aptr) + k0, As + wave * 512);                                                  \
    GL_LDS((aptr) + (size_t)64 * (lda) + k0, As + 2048 + wave * 512);                      \
    GL_LDS((bptr) + k0, Bs + wave * 512);                                                  \
    GL_LDS((bptr) + (size_t)64 * (ldb) + k0, Bs + 2048 + wave * 512);                      \
    __syncthreads();                                                                       \
    bf16x8 aF[4], bF[4];                                                                   \
    _Pragma("unroll") for (int i = 0; i < 4; ++i) aF[i] =                                  \
        *reinterpret_cast<const bf16x8*>(As + (wr * 64 + i * 16 + l16) * 32 + quad * 8);   \
    _Pragma("unroll") for (int j = 0; j < 4; ++j) bF[j] =                                  \
        *reinterpret_cast<const bf16x8*>(Bs + (wc * 64 + j * 16 + l16) * 32 + quad * 8);   \
    _Pragma("unroll") for (int i = 0; i < 4; ++i) _Pragma("unroll") for (int j = 0; j < 4; \
                                                                         ++j) acc[i][j] =  \
        __builtin_amdgcn_mfma_f32_16x16x32_bf16(aF[i], bF[j], acc[i][j], 0, 0, 0);         \
    __syncthreads();                                                                       \
  }

// ---------------- kprep: all casts + new_memory seed, one launch ----------------
__global__ void kprep(const float* __restrict__ hs, const float* __restrict__ wq,
                      const float* __restrict__ wk, const float* __restrict__ wv,
                      const float* __restrict__ wo, const float* __restrict__ mem,
                      __bf16* __restrict__ hsb, __bf16* __restrict__ wqkvb,
                      __bf16* __restrict__ wob, __bf16* __restrict__ memT,
                      float* __restrict__ out) {
  __shared__ float s[64][65];
  int b = blockIdx.x, tid = threadIdx.x;
  if (b < 4096) {  // hs cast: 1M float4 groups
    int i = b * 256 + tid;
    float4 f = reinterpret_cast<const float4*>(hs)[i];
    bf16x4 h = {(__bf16)f.x, (__bf16)f.y, (__bf16)f.z, (__bf16)f.w};
    reinterpret_cast<bf16x4*>(hsb)[i] = h;
  } else if (b < 5120) {  // weight casts: 4 x 65536 groups
    int y = (b - 4096) >> 8;
    const float* src = (y == 0) ? wq : (y == 1) ? wk : (y == 2) ? wv : wo;
    __bf16* dst = (y < 3) ? wqkvb + (size_t)y * (DMEM * HIDDEN) : wob;
    int i = ((b - 4096) & 255) * 256 + tid;
    float4 f = reinterpret_cast<const float4*>(src)[i];
    bf16x4 h = {(__bf16)f.x, (__bf16)f.y, (__bf16)f.z, (__bf16)f.w};
    reinterpret_cast<bf16x4*>(dst)[i] = h;
  } else if (b < 5136) {  // memT transpose-cast: 16 tiles of 64x64
    int t = b - 5120;
    int bx = t & 3, by = t >> 2;
    int r0 = tid >> 6, col = tid & 63;
#pragma unroll
    for (int it = 0; it < 16; ++it) {
      int row = it * 4 + r0;
      s[row][col] = mem[(size_t)(by * 64 + row) * DMEM + bx * 64 + col];
    }
    __syncthreads();
#pragma unroll
    for (int it = 0; it < 16; ++it) {
      int row = it * 4 + r0;
      memT[(size_t)(bx * 64 + row) * DMEM + by * 64 + col] = (__bf16)s[col][row];
    }
  } else {  // seed new_memory region of out with mem (float4): 16384 groups
    int g = (b - 5136) * 256 + tid;
    reinterpret_cast<float4*>(out + (size_t)MTOT * HIDDEN)[g] =
        reinterpret_cast<const float4*>(mem)[g];
  }
}

// ---------------- K1: fused QKV projection, 128x128 MFMA ----------------
// grid (32, 6): m0=bx*128; by: 0,1=q n0 0/128; 2,3=k; 4,5=v.
__global__ __launch_bounds__(256) void k1_qkv_mfma(
    const __bf16* __restrict__ X, const __bf16* __restrict__ W, __bf16* __restrict__ sqb,
    __bf16* __restrict__ skb, __bf16* __restrict__ skT, __bf16* __restrict__ vT) {
  __shared__ __bf16 As[128 * 32];
  __shared__ __bf16 Bs[128 * 32];
  int tid = threadIdx.x;
  int lane = tid & 63, wave = tid >> 6;
  int m0 = blockIdx.x * 128;
  int by = blockIdx.y;
  int wsel = by >> 1, n0 = (by & 1) * 128;
  const __bf16* aptr = X + (size_t)(m0 + (tid >> 2)) * HIDDEN + ((tid & 3) << 3);
  const __bf16* bptr = W + (size_t)(by * 128 + (tid >> 2)) * HIDDEN + ((tid & 3) << 3);
  int wr = wave >> 1, wc = wave & 1, quad = lane >> 4, l16 = lane & 15;
  f32x4 acc[4][4] = {};
  GEMM128_K(aptr, HIDDEN, bptr, HIDDEN, HIDDEN);
#pragma unroll
  for (int i = 0; i < 4; ++i)
#pragma unroll
    for (int j = 0; j < 4; ++j) {
      int mb = m0 + wr * 64 + i * 16 + quad * 4;
      int n = n0 + wc * 64 + j * 16 + l16;
      if (wsel == 0) {
#pragma unroll
        for (int r = 0; r < 4; ++r) sqb[(size_t)(mb + r) * DMEM + n] = (__bf16)elu1(acc[i][j][r]);
      } else if (wsel == 1) {
        bf16x4 t;
#pragma unroll
        for (int r = 0; r < 4; ++r) {
          float v = elu1(acc[i][j][r]);
          skb[(size_t)(mb + r) * DMEM + n] = (__bf16)v;
          t[r] = (__bf16)v;
        }
        *reinterpret_cast<bf16x4*>(skT + (size_t)n * MTOT + mb) = t;
      } else {
        bf16x4 t;
#pragma unroll
        for (int r = 0; r < 4; ++r) t[r] = (__bf16)acc[i][j][r];
        *reinterpret_cast<bf16x4*>(vT + (size_t)n * MTOT + mb) = t;
      }
    }
}

// ---------------- K2: chunk KV sums (64x128 tiles) + fused per-chunk ksum ----------------
// grid (NCHT, 9). y<8: kvcT[c][e][d] = sum_s vT[e,s]*skT[d,s]; y==8: ksc[c][d]=sum_i skb.
__global__ __launch_bounds__(256) void k2_mfma(const __bf16* __restrict__ vT,
                                               const __bf16* __restrict__ skT,
                                               const __bf16* __restrict__ skb,
                                               float* __restrict__ kvcT,
                                               float* __restrict__ ksc) {
  __shared__ __bf16 As[64 * 32];
  __shared__ __bf16 Bs[128 * 32];
  int tid = threadIdx.x;
  int c = blockIdx.x;
  if (blockIdx.y == 8) {
    int d = tid;
    float s = 0.f;
    for (int i = 0; i < CHUNK; ++i) s += (float)skb[(size_t)(c * CHUNK + i) * DMEM + d];
    ksc[c * DMEM + d] = s;
    return;
  }
  int lane = tid & 63, wave = tid >> 6;
  int e0 = (blockIdx.y >> 1) * 64, d0 = (blockIdx.y & 1) * 128;
  const __bf16* aptr = vT + (size_t)(e0 + (tid >> 2)) * MTOT + c * CHUNK + ((tid & 3) << 3);
  const __bf16* bptr = skT + (size_t)(d0 + (tid >> 2)) * MTOT + c * CHUNK + ((tid & 3) << 3);
  int wr = wave >> 1, wc = wave & 1, quad = lane >> 4, l16 = lane & 15;
  f32x4 acc[2][4] = {};
  for (int k0 = 0; k0 < CHUNK; k0 += 32) {
    GL_LDS(aptr + k0, As + wave * 512);
    GL_LDS(bptr + k0, Bs + wave * 512);
    GL_LDS(bptr + (size_t)64 * MTOT + k0, Bs + 2048 + wave * 512);
    __syncthreads();
    bf16x8 aF[2], bF[4];
#pragma unroll
    for (int i = 0; i < 2; ++i)
      aF[i] = *reinterpret_cast<const bf16x8*>(As + (wr * 32 + i * 16 + l16) * 32 + quad * 8);
#pragma unroll
    for (int j = 0; j < 4; ++j)
      bF[j] = *reinterpret_cast<const bf16x8*>(Bs + (wc * 64 + j * 16 + l16) * 32 + quad * 8);
#pragma unroll
    for (int i = 0; i < 2; ++i)
#pragma unroll
      for (int j = 0; j < 4; ++j)
        acc[i][j] = __builtin_amdgcn_mfma_f32_16x16x32_bf16(aF[i], bF[j], acc[i][j], 0, 0, 0);
    __syncthreads();
  }
#pragma unroll
  for (int i = 0; i < 2; ++i)
#pragma unroll
    for (int j = 0; j < 4; ++j)
#pragma unroll
      for (int r = 0; r < 4; ++r) {
        int e = e0 + wr * 32 + i * 16 + quad * 4 + r;
        int d = d0 + wc * 64 + j * 16 + l16;
        kvcT[(size_t)c * DMEM * DMEM + (size_t)e * DMEM + d] = acc[i][j][r];
      }
}

// ---- K3: exclusive chunk prefix (kvcT fp32 -> kvpT bf16; ksc -> ksp) + flag ----
__global__ void k3_prefix(const float* __restrict__ kvcT, __bf16* __restrict__ kvpT,
                          const float* __restrict__ ksc, float* __restrict__ ksp,
                          const float* __restrict__ mnorm, float* __restrict__ flag) {
  int b = blockIdx.x;
  if (b < 1024) {
    int batch = b >> 8;
    int idx = (b & 255) * 256 + threadIdx.x;
    float run = 0.f;
    for (int c = 0; c < NCH; ++c) {
      size_t off = (size_t)(batch * NCH + c) * DMEM * DMEM + idx;
      kvpT[off] = (__bf16)run;
      run += kvcT[off];
    }
  } else if (b < 1028) {
    int batch = b - 1024;
    int d = threadIdx.x;
    float run = 0.f;
    for (int c = 0; c < NCH; ++c) {
      int off = (batch * NCH + c) * DMEM + d;
      ksp[off] = run;
      run += ksc[off];
    }
  } else {
    __shared__ float red[256];
    red[threadIdx.x] = mnorm[threadIdx.x];
    __syncthreads();
    for (int s = 128; s > 0; s >>= 1) {
      if (threadIdx.x < s) red[threadIdx.x] += red[threadIdx.x + s];
      __syncthreads();
    }
    if (threadIdx.x == 0) *flag = (red[0] < EPSF) ? 0.f : 1.f;
  }
}

// ---- K4a: intra-chunk causal scores -> bf16 (64x128 tiles). grid (NCHT, 2). ----
__global__ __launch_bounds__(256) void k4a_mfma(const __bf16* __restrict__ sqb,
                                                const __bf16* __restrict__ skb,
                                                __bf16* __restrict__ scb) {
  __shared__ __bf16 As[64 * 32];
  __shared__ __bf16 Bs[128 * 32];
  int tid = threadIdx.x;
  int lane = tid & 63, wave = tid >> 6;
  int c = blockIdx.x;
  int i0 = blockIdx.y * 64;
  const __bf16* aptr = sqb + (size_t)(c * CHUNK + i0 + (tid >> 2)) * DMEM + ((tid & 3) << 3);
  const __bf16* bptr = skb + (size_t)(c * CHUNK + (tid >> 2)) * DMEM + ((tid & 3) << 3);
  int wr = wave >> 1, wc = wave & 1, quad = lane >> 4, l16 = lane & 15;
  f32x4 acc[2][4] = {};
  for (int k0 = 0; k0 < DMEM; k0 += 32) {
    GL_LDS(aptr + k0, As + wave * 512);
    GL_LDS(bptr + k0, Bs + wave * 512);
    GL_LDS(bptr + (size_t)64 * DMEM + k0, Bs + 2048 + wave * 512);
    __syncthreads();
    bf16x8 aF[2], bF[4];
#pragma unroll
    for (int i = 0; i < 2; ++i)
      aF[i] = *reinterpret_cast<const bf16x8*>(As + (wr * 32 + i * 16 + l16) * 32 + quad * 8);
#pragma unroll
    for (int j = 0; j < 4; ++j)
      bF[j] = *reinterpret_cast<const bf16x8*>(Bs + (wc * 64 + j * 16 + l16) * 32 + quad * 8);
#pragma unroll
    for (int i = 0; i < 2; ++i)
#pragma unroll
      for (int j = 0; j < 4; ++j)
        acc[i][j] = __builtin_amdgcn_mfma_f32_16x16x32_bf16(aF[i], bF[j], acc[i][j], 0, 0, 0);
    __syncthreads();
  }
#pragma unroll
  for (int i = 0; i < 2; ++i)
#pragma unroll
    for (int j = 0; j < 4; ++j)
#pragma unroll
      for (int r = 0; r < 4; ++r) {
        int ii = i0 + wr * 32 + i * 16 + quad * 4 + r;
        int jj = wc * 64 + j * 16 + l16;
        scb[(size_t)c * CHUNK * CHUNK + (size_t)ii * CHUNK + jj] =
            (jj <= ii) ? (__bf16)acc[i][j][r] : (__bf16)0.f;
      }
}

// ---- K4p: per-row scalars (bf16 inputs) ----
__global__ __launch_bounds__(256) void k4p_rows(const __bf16* __restrict__ scb,
                                                const __bf16* __restrict__ sqb,
                                                const __bf16* __restrict__ skb,
                                                const float* __restrict__ ksp,
                                                const float* __restrict__ mnorm,
                                                float* __restrict__ den, float* __restrict__ qn,
                                                float* __restrict__ kn) {
  int wave = threadIdx.x >> 6;
  int lane = threadIdx.x & 63;
  int m = blockIdx.x * 4 + wave;
  int c = m / CHUNK;
  int i = m % CHUNK;
  float s_sc = 0.f, s_d2 = 0.f, s_qn = 0.f, s_kn = 0.f;
  for (int j = lane; j < CHUNK; j += 64)
    s_sc += (float)scb[(size_t)c * CHUNK * CHUNK + (size_t)i * CHUNK + j];
  for (int d = lane; d < DMEM; d += 64) {
    float q = (float)sqb[(size_t)m * DMEM + d];
    float k = (float)skb[(size_t)m * DMEM + d];
    s_d2 += q * ksp[c * DMEM + d];
    s_qn += q * mnorm[d];
    s_kn += k * mnorm[d];
  }
#pragma unroll
  for (int off = 32; off > 0; off >>= 1) {
    s_sc += __shfl_down(s_sc, off);
    s_d2 += __shfl_down(s_d2, off);
    s_qn += __shfl_down(s_qn, off);
    s_kn += __shfl_down(s_kn, off);
  }
  if (lane == 0) {
    den[m] = s_sc + s_d2;
    qn[m] = s_qn;
    kn[m] = s_kn;
  }
}

// ---- K4b (fused K5): local + retrieval + gate combine -> combb. grid (NCHT,4). ----
__global__ __launch_bounds__(256) void k4b_fused(
    const __bf16* __restrict__ scb, const __bf16* __restrict__ sqb,
    const __bf16* __restrict__ vT, const __bf16* __restrict__ kvpT,
    const __bf16* __restrict__ memT, const float* __restrict__ den,
    const float* __restrict__ qn, const float* __restrict__ gate,
    const float* __restrict__ flag, __bf16* __restrict__ combb) {
  __shared__ __bf16 As[64 * 32];
  __shared__ __bf16 B1s[128 * 32];
  __shared__ __bf16 B2s[128 * 32];
  int tid = threadIdx.x;
  int lane = tid & 63, wave = tid >> 6;
  int c = blockIdx.x;
  int i0 = (blockIdx.y >> 1) * 64, e0 = (blockIdx.y & 1) * 128;
  int wr = wave >> 1, wc = wave & 1, quad = lane >> 4, l16 = lane & 15;
  f32x4 acc_loc[2][4] = {};
  f32x4 acc_mem[2][4] = {};
  {
    const __bf16* aptr =
        scb + (size_t)c * CHUNK * CHUNK + (size_t)(i0 + (tid >> 2)) * CHUNK + ((tid & 3) << 3);
    const __bf16* bptr = vT + (size_t)(e0 + (tid >> 2)) * MTOT + c * CHUNK + ((tid & 3) << 3);
    for (int k0 = 0; k0 < CHUNK; k0 += 32) {
      GL_LDS(aptr + k0, As + wave * 512);
      GL_LDS(bptr + k0, B1s + wave * 512);
      GL_LDS(bptr + (size_t)64 * MTOT + k0, B1s + 2048 + wave * 512);
      __syncthreads();
      bf16x8 aF[2], bF[4];
#pragma unroll
      for (int i = 0; i < 2; ++i)
        aF[i] = *reinterpret_cast<const bf16x8*>(As + (wr * 32 + i * 16 + l16) * 32 + quad * 8);
#pragma unroll
      for (int j = 0; j < 4; ++j)
        bF[j] = *reinterpret_cast<const bf16x8*>(B1s + (wc * 64 + j * 16 + l16) * 32 + quad * 8);
#pragma unroll
      for (int i = 0; i < 2; ++i)
#pragma unroll
        for (int j = 0; j < 4; ++j)
          acc_loc[i][j] =
              __builtin_amdgcn_mfma_f32_16x16x32_bf16(aF[i], bF[j], acc_loc[i][j], 0, 0, 0);
      __syncthreads();
    }
  }
  {
    const __bf16* aptr = sqb + (size_t)(c * CHUNK + i0 + (tid >> 2)) * DMEM + ((tid & 3) << 3);
    const __bf16* b1ptr =
        kvpT + (size_t)c * DMEM * DMEM + (size_t)(e0 + (tid >> 2)) * DMEM + ((tid & 3) << 3);
    const __bf16* b2ptr = memT + (size_t)(e0 + (tid >> 2)) * DMEM + ((tid & 3) << 3);
    for (int k0 = 0; k0 < DMEM; k0 += 32) {
      GL_LDS(aptr + k0, As + wave * 512);
      GL_LDS(b1ptr + k0, B1s + wave * 512);
      GL_LDS(b1ptr + (size_t)64 * DMEM + k0, B1s + 2048 + wave * 512);
      GL_LDS(b2ptr + k0, B2s + wave * 512);
      GL_LDS(b2ptr + (size_t)64 * DMEM + k0, B2s + 2048 + wave * 512);
      __syncthreads();
      bf16x8 aF[2], b1F[4], b2F[4];
#pragma unroll
      for (int i = 0; i < 2; ++i)
        aF[i] = *reinterpret_cast<const bf16x8*>(As + (wr * 32 + i * 16 + l16) * 32 + quad * 8);
#pragma unroll
      for (int j = 0; j < 4; ++j) {
        b1F[j] = *reinterpret_cast<const bf16x8*>(B1s + (wc * 64 + j * 16 + l16) * 32 + quad * 8);
        b2F[j] = *reinterpret_cast<const bf16x8*>(B2s + (wc * 64 + j * 16 + l16) * 32 + quad * 8);
      }
#pragma unroll
      for (int i = 0; i < 2; ++i)
#pragma unroll
        for (int j = 0; j < 4; ++j) {
          acc_loc[i][j] =
              __builtin_amdgcn_mfma_f32_16x16x32_bf16(aF[i], b1F[j], acc_loc[i][j], 0, 0, 0);
          acc_mem[i][j] =
              __builtin_amdgcn_mfma_f32_16x16x32_bf16(aF[i], b2F[j], acc_mem[i][j], 0, 0, 0);
        }
      __syncthreads();
    }
  }
  float g = 1.f / (1.f + __expf(-gate[0]));
  float fl = *flag;
#pragma unroll
  for (int i = 0; i < 2; ++i) {
    int mb = c * CHUNK + i0 + wr * 32 + i * 16 + quad * 4;
    float dn[4], qv[4];
#pragma unroll
    for (int r = 0; r < 4; ++r) {
      dn[r] = fmaxf(den[mb + r], EPSF);
      qv[r] = fmaxf(qn[mb + r], EPSF);
    }
#pragma unroll
    for (int j = 0; j < 4; ++j) {
      int e = e0 + wc * 64 + j * 16 + l16;
#pragma unroll
      for (int r = 0; r < 4; ++r) {
        float comb = g * fl * acc_mem[i][j][r] / qv[r] + (1.f - g) * acc_loc[i][j][r] / dn[r];
        combb[(size_t)(mb + r) * DMEM + e] = (__bf16)comb;
      }
    }
  }
}

// ---------------- K6: output projection, 128x128 MFMA. grid (32, 8). ----------------
__global__ __launch_bounds__(256) void k6_out_mfma(const __bf16* __restrict__ A,
                                                   const __bf16* __restrict__ B,
                                                   float* __restrict__ out) {
  __shared__ __bf16 As[128 * 32];
  __shared__ __bf16 Bs[128 * 32];
  int tid = threadIdx.x;
  int lane = tid & 63, wave = tid >> 6;
  int m0 = blockIdx.x * 128;
  int by = blockIdx.y;
  const __bf16* aptr = A + (size_t)(m0 + (tid >> 2)) * DMEM + ((tid & 3) << 3);
  const __bf16* bptr = B + (size_t)(by * 128 + (tid >> 2)) * DMEM + ((tid & 3) << 3);
  int wr = wave >> 1, wc = wave & 1, quad = lane >> 4, l16 = lane & 15;
  f32x4 acc[4][4] = {};
  GEMM128_K(aptr, DMEM, bptr, DMEM, DMEM);
#pragma unroll
  for (int i = 0; i < 4; ++i)
#pragma unroll
    for (int j = 0; j < 4; ++j)
#pragma unroll
      for (int r = 0; r < 4; ++r) {
        int m = m0 + wr * 64 + i * 16 + quad * 4 + r;
        int n = by * 128 + wc * 64 + j * 16 + l16;
        out[(size_t)m * HIDDEN + n] = acc[i][j][r];
      }
}

// ---- K7a: dv = v - (skb@memT)/kn -> dvT bf16. 128x128 MFMA. grid (32,2). ----
__global__ __launch_bounds__(256) void k7a_mfma(const __bf16* __restrict__ skb,
                                                const __bf16* __restrict__ memT,
                                                const float* __restrict__ kn,
                                                const __bf16* __restrict__ vT,
                                                __bf16* __restrict__ dvT) {
  __shared__ __bf16 As[128 * 32];
  __shared__ __bf16 Bs[128 * 32];
  int tid = threadIdx.x;
  int lane = tid & 63, wave = tid >> 6;
  int m0 = blockIdx.x * 128;
  int n0 = blockIdx.y * 128;
  const __bf16* aptr = skb + (size_t)(m0 + (tid >> 2)) * DMEM + ((tid & 3) << 3);
  const __bf16* bptr = memT + (size_t)(n0 + (tid >> 2)) * DMEM + ((tid & 3) << 3);
  int wr = wave >> 1, wc = wave & 1, quad = lane >> 4, l16 = lane & 15;
  f32x4 acc[4][4] = {};
  GEMM128_K(aptr, DMEM, bptr, DMEM, DMEM);
#pragma unroll
  for (int i = 0; i < 4; ++i) {
    int mb = m0 + wr * 64 + i * 16 + quad * 4;
    float kv[4];
#pragma unroll
    for (int r = 0; r < 4; ++r) kv[r] = fmaxf(kn[mb + r], EPSF);
#pragma unroll
    for (int j = 0; j < 4; ++j) {
      int n = n0 + wc * 64 + j * 16 + l16;
      bf16x4 vv = *reinterpret_cast<const bf16x4*>(vT + (size_t)n * MTOT + mb);
      bf16x4 t;
#pragma unroll
      for (int r = 0; r < 4; ++r) t[r] = (__bf16)((float)vv[r] - acc[i][j][r] / kv[r]);
      *reinterpret_cast<bf16x4*>(dvT + (size_t)n * MTOT + mb) = t;
    }
  }
}

// ---- K7b: memory_update split-K MFMA + fused k7c norm. grid (16, 9). ----
__global__ __launch_bounds__(256) void k7b_mfma(const __bf16* __restrict__ skT,
                                                const __bf16* __restrict__ dvT,
                                                const float* __restrict__ ksc,
                                                const float* __restrict__ mnorm,
                                                float* __restrict__ out) {
  __shared__ __bf16 As[64 * 32];
  __shared__ __bf16 Bs[128 * 32];
  int tid = threadIdx.x;
  if (blockIdx.y == 8) {
    if (blockIdx.x != 0) return;
    int d = tid;
    float s = 0.f;
    for (int c = 0; c < NCHT; ++c) s += ksc[c * DMEM + d];
    out[(size_t)MTOT * HIDDEN + DMEM * DMEM + d] = mnorm[d] + s * (1.f / (float)BATCH);
    return;
  }
  int lane = tid & 63, wave = tid >> 6;
  int kbase = blockIdx.x * 256;
  int d0 = (blockIdx.y >> 1) * 64, e0 = (blockIdx.y & 1) * 128;
  const __bf16* aptr = skT + (size_t)(d0 + (tid >> 2)) * MTOT + kbase + ((tid & 3) << 3);
  const __bf16* bptr = dvT + (size_t)(e0 + (tid >> 2)) * MTOT + kbase + ((tid & 3) << 3);
  int wr = wave >> 1, wc = wave & 1, quad = lane >> 4, l16 = lane & 15;
  f32x4 acc[2][4] = {};
  for (int k0 = 0; k0 < 256; k0 += 32) {
    GL_LDS(aptr + k0, As + wave * 512);
    GL_LDS(bptr + k0, Bs + wave * 512);
    GL_LDS(bptr + (size_t)64 * MTOT + k0, Bs + 2048 + wave * 512);
    __syncthreads();
    bf16x8 aF[2], bF[4];
#pragma unroll
    for (int i = 0; i < 2; ++i)
      aF[i] = *reinterpret_cast<const bf16x8*>(As + (wr * 32 + i * 16 + l16) * 32 + quad * 8);
#pragma unroll
    for (int j = 0; j < 4; ++j)
      bF[j] = *reinterpret_cast<const bf16x8*>(Bs + (wc * 64 + j * 16 + l16) * 32 + quad * 8);
#pragma unroll
    for (int i = 0; i < 2; ++i)
#pragma unroll
      for (int j = 0; j < 4; ++j)
        acc[i][j] = __builtin_amdgcn_mfma_f32_16x16x32_bf16(aF[i], bF[j], acc[i][j], 0, 0, 0);
    __syncthreads();
  }
  float* base = out + (size_t)MTOT * HIDDEN;
#pragma unroll
  for (int i = 0; i < 2; ++i)
#pragma unroll
    for (int j = 0; j < 4; ++j)
#pragma unroll
      for (int r = 0; r < 4; ++r) {
        int d = d0 + wr * 32 + i * 16 + quad * 4 + r;
        int e = e0 + wc * 64 + j * 16 + l16;
        atomicAdd(&base[(size_t)d * DMEM + e], acc[i][j][r] * (1.f / (float)MTOT));
      }
}

extern "C" void kernel_launch(void* const* d_in, const int* in_sizes, int n_in,
                              void* d_out, int out_size, void* d_ws, size_t ws_size,
                              hipStream_t stream) {
  const float* hs = (const float*)d_in[0];
  const float* wq = (const float*)d_in[1];
  const float* wk = (const float*)d_in[2];
  const float* wv = (const float*)d_in[3];
  const float* wo = (const float*)d_in[4];
  const float* gate = (const float*)d_in[5];
  const float* mem = (const float*)d_in[6];
  const float* mnorm = (const float*)d_in[7];
  float* out = (float*)d_out;
  float* ws = (float*)d_ws;

  // fp32 region
  float* kvcT = ws;                                // 2097152
  float* ksc = kvcT + (size_t)NCHT * DMEM * DMEM;  // 8192
  float* ksp = ksc + NCHT * DMEM;                  // 8192
  float* den = ksp + NCHT * DMEM;                  // 4096
  float* qn = den + MTOT;                          // 4096
  float* kn = qn + MTOT;                           // 4096
  float* flag = kn + MTOT;                         // 4 (pad)
  // bf16 region (16B aligned)
  __bf16* hsb = (__bf16*)(flag + 4);                  // 4194304
  __bf16* wqkvb = hsb + (size_t)MTOT * HIDDEN;        // 786432
  __bf16* wob = wqkvb + (size_t)3 * DMEM * HIDDEN;    // 262144
  __bf16* memT = wob + (size_t)HIDDEN * DMEM;         // 65536
  __bf16* sqb = memT + (size_t)DMEM * DMEM;           // 1048576
  __bf16* skb = sqb + (size_t)MTOT * DMEM;            // 1048576
  __bf16* skT = skb + (size_t)MTOT * DMEM;            // 1048576
  __bf16* vT = skT + (size_t)MTOT * DMEM;             // 1048576
  __bf16* scb = vT + (size_t)MTOT * DMEM;             // 524288
  __bf16* kvpT = scb + (size_t)NCHT * CHUNK * CHUNK;  // 2097152
  __bf16* combb = kvpT + (size_t)NCHT * DMEM * DMEM;  // 1048576
  __bf16* dvT = combb + (size_t)MTOT * DMEM;          // 1048576

  kprep<<<dim3(5200), 256, 0, stream>>>(hs, wq, wk, wv, wo, mem, hsb, wqkvb, wob, memT, out);
  k1_qkv_mfma<<<dim3(32, 6), 256, 0, stream>>>(hsb, wqkvb, sqb, skb, skT, vT);
  k2_mfma<<<dim3(NCHT, 9), 256, 0, stream>>>(vT, skT, skb, kvcT, ksc);
  k3_prefix<<<dim3(1029), 256, 0, stream>>>(kvcT, kvpT, ksc, ksp, mnorm, flag);
  k4a_mfma<<<dim3(NCHT, 2), 256, 0, stream>>>(sqb, skb, scb);
  k4p_rows<<<dim3(MTOT / 4), 256, 0, stream>>>(scb, sqb, skb, ksp, mnorm, den, qn, kn);
  k4b_fused<<<dim3(NCHT, 4), 256, 0, stream>>>(scb, sqb, vT, kvpT, memT, den, qn, gate, flag,
                                               combb);
  k6_out_mfma<<<dim3(32, 8), 256, 0, stream>>>(combb, wob, out);
  k7a_mfma<<<dim3(32, 2), 256, 0, stream>>>(skb, memT, kn, vT, dvT);
  k7b_mfma<<<dim3(16, 9), 256, 0, stream>>>(skT, dvT, ksc, mnorm, out);
}

// Round 8
// 148.813 us; speedup vs baseline: 2.4589x; 1.1723x over previous
//
#include <hip/hip_runtime.h>

// InfiniAttention — Round 8: revert to R4 multi-kernel structure (cooperative path
// abandoned: coop-kernel ws writes not reliably visible to later dispatches).
// Consolidated 10 -> 6 dispatches; kvcT stored bf16; ksp computed on-the-fly in k4p.

#define HIDDEN 1024
#define DMEM 256
#define BATCH 4
#define SEQ 1024
#define MTOT (BATCH * SEQ)      // 4096
#define CHUNK 128
#define NCH (SEQ / CHUNK)       // 8
#define NCHT (BATCH * NCH)      // 32
#define EPSF 1e-6f

typedef __bf16 bf16x8 __attribute__((ext_vector_type(8)));
typedef __bf16 bf16x4 __attribute__((ext_vector_type(4)));
typedef float f32x4 __attribute__((ext_vector_type(4)));

#define GL_LDS(g, l)                                                                   \
  __builtin_amdgcn_global_load_lds((const __attribute__((address_space(1))) void*)(g), \
                                   (__attribute__((address_space(3))) void*)(l), 16, 0, 0)

__device__ __forceinline__ float elu1(float x) { return x > 0.f ? x + 1.f : __expf(x); }

// ---------------- kprep: all casts + new_memory seed (unchanged from R4) ----------------
__global__ void kprep(const float* __restrict__ hs, const float* __restrict__ wq,
                      const float* __restrict__ wk, const float* __restrict__ wv,
                      const float* __restrict__ wo, const float* __restrict__ mem,
                      __bf16* __restrict__ hsb, __bf16* __restrict__ wqkvb,
                      __bf16* __restrict__ wob, __bf16* __restrict__ memT,
                      float* __restrict__ out) {
  __shared__ float s[64][65];
  int b = blockIdx.x, tid = threadIdx.x;
  if (b < 4096) {
    int i = b * 256 + tid;
    float4 f = reinterpret_cast<const float4*>(hs)[i];
    bf16x4 h = {(__bf16)f.x, (__bf16)f.y, (__bf16)f.z, (__bf16)f.w};
    reinterpret_cast<bf16x4*>(hsb)[i] = h;
  } else if (b < 5120) {
    int y = (b - 4096) >> 8;
    const float* src = (y == 0) ? wq : (y == 1) ? wk : (y == 2) ? wv : wo;
    __bf16* dst = (y < 3) ? wqkvb + (size_t)y * (DMEM * HIDDEN) : wob;
    int i = ((b - 4096) & 255) * 256 + tid;
    float4 f = reinterpret_cast<const float4*>(src)[i];
    bf16x4 h = {(__bf16)f.x, (__bf16)f.y, (__bf16)f.z, (__bf16)f.w};
    reinterpret_cast<bf16x4*>(dst)[i] = h;
  } else if (b < 5136) {
    int t = b - 5120;
    int bx = t & 3, by = t >> 2;
    int r0 = tid >> 6, col = tid & 63;
#pragma unroll
    for (int it = 0; it < 16; ++it) {
      int row = it * 4 + r0;
      s[row][col] = mem[(size_t)(by * 64 + row) * DMEM + bx * 64 + col];
    }
    __syncthreads();
#pragma unroll
    for (int it = 0; it < 16; ++it) {
      int row = it * 4 + r0;
      memT[(size_t)(bx * 64 + row) * DMEM + by * 64 + col] = (__bf16)s[col][row];
    }
  } else {
    int g = (b - 5136) * 256 + tid;
    reinterpret_cast<float4*>(out + (size_t)MTOT * HIDDEN)[g] =
        reinterpret_cast<const float4*>(mem)[g];
  }
}

// ---------------- K1: fused QKV projection, 128x128 MFMA (unchanged from R4) ----------------
__global__ __launch_bounds__(256) void k1_qkv_mfma(
    const __bf16* __restrict__ X, const __bf16* __restrict__ W, __bf16* __restrict__ sqb,
    __bf16* __restrict__ skb, __bf16* __restrict__ skT, __bf16* __restrict__ vT) {
  __shared__ __bf16 As[128 * 32];
  __shared__ __bf16 Bs[128 * 32];
  int tid = threadIdx.x;
  int lane = tid & 63, wave = tid >> 6;
  int m0 = blockIdx.x * 128;
  int by = blockIdx.y;
  int wsel = by >> 1, n0 = (by & 1) * 128;
  const __bf16* aptr = X + (size_t)(m0 + (tid >> 2)) * HIDDEN + ((tid & 3) << 3);
  const __bf16* bptr = W + (size_t)(by * 128 + (tid >> 2)) * HIDDEN + ((tid & 3) << 3);
  int wr = wave >> 1, wc = wave & 1, quad = lane >> 4, l16 = lane & 15;
  f32x4 acc[4][4] = {};
  for (int k0 = 0; k0 < HIDDEN; k0 += 32) {
    GL_LDS(aptr + k0, As + wave * 512);
    GL_LDS(aptr + (size_t)64 * HIDDEN + k0, As + 2048 + wave * 512);
    GL_LDS(bptr + k0, Bs + wave * 512);
    GL_LDS(bptr + (size_t)64 * HIDDEN + k0, Bs + 2048 + wave * 512);
    __syncthreads();
    bf16x8 aF[4], bF[4];
#pragma unroll
    for (int i = 0; i < 4; ++i)
      aF[i] = *reinterpret_cast<const bf16x8*>(As + (wr * 64 + i * 16 + l16) * 32 + quad * 8);
#pragma unroll
    for (int j = 0; j < 4; ++j)
      bF[j] = *reinterpret_cast<const bf16x8*>(Bs + (wc * 64 + j * 16 + l16) * 32 + quad * 8);
#pragma unroll
    for (int i = 0; i < 4; ++i)
#pragma unroll
      for (int j = 0; j < 4; ++j)
        acc[i][j] = __builtin_amdgcn_mfma_f32_16x16x32_bf16(aF[i], bF[j], acc[i][j], 0, 0, 0);
    __syncthreads();
  }
#pragma unroll
  for (int i = 0; i < 4; ++i)
#pragma unroll
    for (int j = 0; j < 4; ++j) {
      int mb = m0 + wr * 64 + i * 16 + quad * 4;
      int n = n0 + wc * 64 + j * 16 + l16;
      if (wsel == 0) {
#pragma unroll
        for (int r = 0; r < 4; ++r) sqb[(size_t)(mb + r) * DMEM + n] = (__bf16)elu1(acc[i][j][r]);
      } else if (wsel == 1) {
        bf16x4 t;
#pragma unroll
        for (int r = 0; r < 4; ++r) {
          float v = elu1(acc[i][j][r]);
          skb[(size_t)(mb + r) * DMEM + n] = (__bf16)v;
          t[r] = (__bf16)v;
        }
        *reinterpret_cast<bf16x4*>(skT + (size_t)n * MTOT + mb) = t;
      } else {
        bf16x4 t;
#pragma unroll
        for (int r = 0; r < 4; ++r) t[r] = (__bf16)acc[i][j][r];
        *reinterpret_cast<bf16x4*>(vT + (size_t)n * MTOT + mb) = t;
      }
    }
}

// ---------------- kC: chunk-KV (y<8, bf16 out) + causal scores (y=8,9) + ksum (y=10) ------
__global__ __launch_bounds__(256) void kC(const __bf16* __restrict__ vT,
                                          const __bf16* __restrict__ skT,
                                          const __bf16* __restrict__ sqb,
                                          const __bf16* __restrict__ skb,
                                          __bf16* __restrict__ kvcT, __bf16* __restrict__ scb,
                                          float* __restrict__ ksc) {
  __shared__ __bf16 As[64 * 32];
  __shared__ __bf16 Bs[128 * 32];
  int tid = threadIdx.x;
  int c = blockIdx.x;
  int y = blockIdx.y;
  if (y == 10) {
    int d = tid;
    float s = 0.f;
    for (int i = 0; i < CHUNK; ++i) s += (float)skb[(size_t)(c * CHUNK + i) * DMEM + d];
    ksc[c * DMEM + d] = s;
    return;
  }
  int lane = tid & 63, wave = tid >> 6;
  int wr = wave >> 1, wc = wave & 1, quad = lane >> 4, l16 = lane & 15;
  if (y < 8) {  // k2: kvcT[c][e][d] = sum_s vT[e,s]*skT[d,s]
    int e0 = (y >> 1) * 64, d0 = (y & 1) * 128;
    const __bf16* aptr = vT + (size_t)(e0 + (tid >> 2)) * MTOT + c * CHUNK + ((tid & 3) << 3);
    const __bf16* bptr = skT + (size_t)(d0 + (tid >> 2)) * MTOT + c * CHUNK + ((tid & 3) << 3);
    f32x4 acc[2][4] = {};
    for (int k0 = 0; k0 < CHUNK; k0 += 32) {
      GL_LDS(aptr + k0, As + wave * 512);
      GL_LDS(bptr + k0, Bs + wave * 512);
      GL_LDS(bptr + (size_t)64 * MTOT + k0, Bs + 2048 + wave * 512);
      __syncthreads();
      bf16x8 aF[2], bF[4];
#pragma unroll
      for (int i = 0; i < 2; ++i)
        aF[i] = *reinterpret_cast<const bf16x8*>(As + (wr * 32 + i * 16 + l16) * 32 + quad * 8);
#pragma unroll
      for (int j = 0; j < 4; ++j)
        bF[j] = *reinterpret_cast<const bf16x8*>(Bs + (wc * 64 + j * 16 + l16) * 32 + quad * 8);
#pragma unroll
      for (int i = 0; i < 2; ++i)
#pragma unroll
        for (int j = 0; j < 4; ++j)
          acc[i][j] = __builtin_amdgcn_mfma_f32_16x16x32_bf16(aF[i], bF[j], acc[i][j], 0, 0, 0);
      __syncthreads();
    }
#pragma unroll
    for (int i = 0; i < 2; ++i)
#pragma unroll
      for (int j = 0; j < 4; ++j)
#pragma unroll
        for (int r = 0; r < 4; ++r) {
          int e = e0 + wr * 32 + i * 16 + quad * 4 + r;
          int d = d0 + wc * 64 + j * 16 + l16;
          kvcT[(size_t)c * DMEM * DMEM + (size_t)e * DMEM + d] = (__bf16)acc[i][j][r];
        }
  } else {  // k4a: causal scores, i0 = (y-8)*64
    int i0 = (y - 8) * 64;
    const __bf16* aptr =
        sqb + (size_t)(c * CHUNK + i0 + (tid >> 2)) * DMEM + ((tid & 3) << 3);
    const __bf16* bptr = skb + (size_t)(c * CHUNK + (tid >> 2)) * DMEM + ((tid & 3) << 3);
    f32x4 acc[2][4] = {};
    for (int k0 = 0; k0 < DMEM; k0 += 32) {
      GL_LDS(aptr + k0, As + wave * 512);
      GL_LDS(bptr + k0, Bs + wave * 512);
      GL_LDS(bptr + (size_t)64 * DMEM + k0, Bs + 2048 + wave * 512);
      __syncthreads();
      bf16x8 aF[2], bF[4];
#pragma unroll
      for (int i = 0; i < 2; ++i)
        aF[i] = *reinterpret_cast<const bf16x8*>(As + (wr * 32 + i * 16 + l16) * 32 + quad * 8);
#pragma unroll
      for (int j = 0; j < 4; ++j)
        bF[j] = *reinterpret_cast<const bf16x8*>(Bs + (wc * 64 + j * 16 + l16) * 32 + quad * 8);
#pragma unroll
      for (int i = 0; i < 2; ++i)
#pragma unroll
        for (int j = 0; j < 4; ++j)
          acc[i][j] = __builtin_amdgcn_mfma_f32_16x16x32_bf16(aF[i], bF[j], acc[i][j], 0, 0, 0);
      __syncthreads();
    }
#pragma unroll
    for (int i = 0; i < 2; ++i)
#pragma unroll
      for (int j = 0; j < 4; ++j)
#pragma unroll
        for (int r = 0; r < 4; ++r) {
          int ii = i0 + wr * 32 + i * 16 + quad * 4 + r;
          int jj = wc * 64 + j * 16 + l16;
          scb[(size_t)c * CHUNK * CHUNK + (size_t)ii * CHUNK + jj] =
              (jj <= ii) ? (__bf16)acc[i][j][r] : (__bf16)0.f;
        }
  }
}

// ---------------- kD: kvpT exclusive prefix (vt<1024) + row scalars (vt>=1024) ----------------
__global__ __launch_bounds__(256) void kD(const __bf16* __restrict__ kvcT,
                                          __bf16* __restrict__ kvpT,
                                          const float* __restrict__ ksc,
                                          const __bf16* __restrict__ scb,
                                          const __bf16* __restrict__ sqb,
                                          const __bf16* __restrict__ skb,
                                          const float* __restrict__ mnorm,
                                          float* __restrict__ den, float* __restrict__ qn,
                                          float* __restrict__ kn) {
  int vt = blockIdx.x;
  int tid = threadIdx.x;
  if (vt < 1024) {
    int batch = vt >> 8;
    int idx = (vt & 255) * 256 + tid;
    float run = 0.f;
    for (int c = 0; c < NCH; ++c) {
      size_t off = (size_t)(batch * NCH + c) * DMEM * DMEM + idx;
      kvpT[off] = (__bf16)run;
      run += (float)kvcT[off];
    }
  } else {
    int wave = tid >> 6, lane = tid & 63;
    int m = (vt - 1024) * 4 + wave;
    int c = m >> 7;   // chunk index 0..31
    int i = m & 127;
    int cb = c & ~7;  // first chunk of this batch
    float s_sc = 0.f, s_d2 = 0.f, s_qn = 0.f, s_kn = 0.f;
    for (int j = lane; j < CHUNK; j += 64)
      s_sc += (float)scb[(size_t)c * CHUNK * CHUNK + (size_t)i * CHUNK + j];
    for (int d = lane; d < DMEM; d += 64) {
      float q = (float)sqb[(size_t)m * DMEM + d];
      float k = (float)skb[(size_t)m * DMEM + d];
      float kp = 0.f;
      for (int cc = cb; cc < c; ++cc) kp += ksc[cc * DMEM + d];
      s_d2 += q * kp;
      s_qn += q * mnorm[d];
      s_kn += k * mnorm[d];
    }
#pragma unroll
    for (int off = 32; off > 0; off >>= 1) {
      s_sc += __shfl_down(s_sc, off);
      s_d2 += __shfl_down(s_d2, off);
      s_qn += __shfl_down(s_qn, off);
      s_kn += __shfl_down(s_kn, off);
    }
    if (lane == 0) {
      den[m] = s_sc + s_d2;
      qn[m] = s_qn;
      kn[m] = s_kn;
    }
  }
}

// ---------------- kE: combine (bid<128) + delta-v (bid 128..191) ----------------
__global__ __launch_bounds__(256) void kE(const __bf16* __restrict__ scb,
                                          const __bf16* __restrict__ sqb,
                                          const __bf16* __restrict__ skb,
                                          const __bf16* __restrict__ vT,
                                          const __bf16* __restrict__ kvpT,
                                          const __bf16* __restrict__ memT,
                                          const float* __restrict__ den,
                                          const float* __restrict__ qn,
                                          const float* __restrict__ kn,
                                          const float* __restrict__ gate,
                                          const float* __restrict__ mnorm,
                                          __bf16* __restrict__ combb, __bf16* __restrict__ dvT) {
  __shared__ __bf16 As[128 * 32];
  __shared__ __bf16 B1s[128 * 32];
  __shared__ __bf16 B2s[128 * 32];
  __shared__ float flagsh;
  int tid = threadIdx.x;
  int lane = tid & 63, wave = tid >> 6;
  int wr = wave >> 1, wc = wave & 1, quad = lane >> 4, l16 = lane & 15;
  int bid = blockIdx.x;
  if (bid < 128) {  // k4b fused combine
    if (tid == 0) {
      float s = 0.f;
      for (int d = 0; d < DMEM; ++d) s += mnorm[d];
      flagsh = (s < EPSF) ? 0.f : 1.f;
    }
    __syncthreads();
    float fl = flagsh;
    __syncthreads();
    int c = bid >> 2, yy = bid & 3;
    int i0 = (yy >> 1) * 64, e0 = (yy & 1) * 128;
    f32x4 acc_loc[2][4] = {};
    f32x4 acc_mem[2][4] = {};
    {  // phase 1: scores @ v
      const __bf16* aptr =
          scb + (size_t)c * CHUNK * CHUNK + (size_t)(i0 + (tid >> 2)) * CHUNK + ((tid & 3) << 3);
      const __bf16* bptr = vT + (size_t)(e0 + (tid >> 2)) * MTOT + c * CHUNK + ((tid & 3) << 3);
      for (int k0 = 0; k0 < CHUNK; k0 += 32) {
        GL_LDS(aptr + k0, As + wave * 512);
        GL_LDS(bptr + k0, B1s + wave * 512);
        GL_LDS(bptr + (size_t)64 * MTOT + k0, B1s + 2048 + wave * 512);
        __syncthreads();
        bf16x8 aF[2], bF[4];
#pragma unroll
        for (int i = 0; i < 2; ++i)
          aF[i] = *reinterpret_cast<const bf16x8*>(As + (wr * 32 + i * 16 + l16) * 32 + quad * 8);
#pragma unroll
        for (int j = 0; j < 4; ++j)
          bF[j] =
              *reinterpret_cast<const bf16x8*>(B1s + (wc * 64 + j * 16 + l16) * 32 + quad * 8);
#pragma unroll
        for (int i = 0; i < 2; ++i)
#pragma unroll
          for (int j = 0; j < 4; ++j)
            acc_loc[i][j] =
                __builtin_amdgcn_mfma_f32_16x16x32_bf16(aF[i], bF[j], acc_loc[i][j], 0, 0, 0);
        __syncthreads();
      }
    }
    {  // phase 2: sq @ kvp + sq @ memT
      const __bf16* aptr =
          sqb + (size_t)(c * CHUNK + i0 + (tid >> 2)) * DMEM + ((tid & 3) << 3);
      const __bf16* b1ptr =
          kvpT + (size_t)c * DMEM * DMEM + (size_t)(e0 + (tid >> 2)) * DMEM + ((tid & 3) << 3);
      const __bf16* b2ptr = memT + (size_t)(e0 + (tid >> 2)) * DMEM + ((tid & 3) << 3);
      for (int k0 = 0; k0 < DMEM; k0 += 32) {
        GL_LDS(aptr + k0, As + wave * 512);
        GL_LDS(b1ptr + k0, B1s + wave * 512);
        GL_LDS(b1ptr + (size_t)64 * DMEM + k0, B1s + 2048 + wave * 512);
        GL_LDS(b2ptr + k0, B2s + wave * 512);
        GL_LDS(b2ptr + (size_t)64 * DMEM + k0, B2s + 2048 + wave * 512);
        __syncthreads();
        bf16x8 aF[2], b1F[4], b2F[4];
#pragma unroll
        for (int i = 0; i < 2; ++i)
          aF[i] = *reinterpret_cast<const bf16x8*>(As + (wr * 32 + i * 16 + l16) * 32 + quad * 8);
#pragma unroll
        for (int j = 0; j < 4; ++j) {
          b1F[j] =
              *reinterpret_cast<const bf16x8*>(B1s + (wc * 64 + j * 16 + l16) * 32 + quad * 8);
          b2F[j] =
              *reinterpret_cast<const bf16x8*>(B2s + (wc * 64 + j * 16 + l16) * 32 + quad * 8);
        }
#pragma unroll
        for (int i = 0; i < 2; ++i)
#pragma unroll
          for (int j = 0; j < 4; ++j) {
            acc_loc[i][j] =
                __builtin_amdgcn_mfma_f32_16x16x32_bf16(aF[i], b1F[j], acc_loc[i][j], 0, 0, 0);
            acc_mem[i][j] =
                __builtin_amdgcn_mfma_f32_16x16x32_bf16(aF[i], b2F[j], acc_mem[i][j], 0, 0, 0);
          }
        __syncthreads();
      }
    }
    float g = 1.f / (1.f + __expf(-gate[0]));
#pragma unroll
    for (int i = 0; i < 2; ++i) {
      int mb = c * CHUNK + i0 + wr * 32 + i * 16 + quad * 4;
      float dn[4], qv[4];
#pragma unroll
      for (int r = 0; r < 4; ++r) {
        dn[r] = fmaxf(den[mb + r], EPSF);
        qv[r] = fmaxf(qn[mb + r], EPSF);
      }
#pragma unroll
      for (int j = 0; j < 4; ++j) {
        int e = e0 + wc * 64 + j * 16 + l16;
#pragma unroll
        for (int r = 0; r < 4; ++r) {
          float comb = g * fl * acc_mem[i][j][r] / qv[r] + (1.f - g) * acc_loc[i][j][r] / dn[r];
          combb[(size_t)(mb + r) * DMEM + e] = (__bf16)comb;
        }
      }
    }
  } else {  // k7a: dv = v - (sk@memT)/kn -> dvT (128x128 tiles)
    int t = bid - 128;
    int m0 = (t >> 1) * 128, n0 = (t & 1) * 128;
    const __bf16* aptr = skb + (size_t)(m0 + (tid >> 2)) * DMEM + ((tid & 3) << 3);
    const __bf16* bptr = memT + (size_t)(n0 + (tid >> 2)) * DMEM + ((tid & 3) << 3);
    f32x4 acc[4][4] = {};
    for (int k0 = 0; k0 < DMEM; k0 += 32) {
      GL_LDS(aptr + k0, As + wave * 512);
      GL_LDS(aptr + (size_t)64 * DMEM + k0, As + 2048 + wave * 512);
      GL_LDS(bptr + k0, B1s + wave * 512);
      GL_LDS(bptr + (size_t)64 * DMEM + k0, B1s + 2048 + wave * 512);
      __syncthreads();
      bf16x8 aF[4], bF[4];
#pragma unroll
      for (int i = 0; i < 4; ++i)
        aF[i] = *reinterpret_cast<const bf16x8*>(As + (wr * 64 + i * 16 + l16) * 32 + quad * 8);
#pragma unroll
      for (int j = 0; j < 4; ++j)
        bF[j] = *reinterpret_cast<const bf16x8*>(B1s + (wc * 64 + j * 16 + l16) * 32 + quad * 8);
#pragma unroll
      for (int i = 0; i < 4; ++i)
#pragma unroll
        for (int j = 0; j < 4; ++j)
          acc[i][j] = __builtin_amdgcn_mfma_f32_16x16x32_bf16(aF[i], bF[j], acc[i][j], 0, 0, 0);
      __syncthreads();
    }
#pragma unroll
    for (int i = 0; i < 4; ++i) {
      int mb = m0 + wr * 64 + i * 16 + quad * 4;
      float kv[4];
#pragma unroll
      for (int r = 0; r < 4; ++r) kv[r] = fmaxf(kn[mb + r], EPSF);
#pragma unroll
      for (int j = 0; j < 4; ++j) {
        int n = n0 + wc * 64 + j * 16 + l16;
        bf16x4 vv = *reinterpret_cast<const bf16x4*>(vT + (size_t)n * MTOT + mb);
        bf16x4 tt;
#pragma unroll
        for (int r = 0; r < 4; ++r) tt[r] = (__bf16)((float)vv[r] - acc[i][j][r] / kv[r]);
        *reinterpret_cast<bf16x4*>(dvT + (size_t)n * MTOT + mb) = tt;
      }
    }
  }
}

// ---------------- kF: out-proj (bid<256) + mem update (256..383) + norm (384) ----------------
__global__ __launch_bounds__(256) void kF(const __bf16* __restrict__ combb,
                                          const __bf16* __restrict__ wob,
                                          const __bf16* __restrict__ skT,
                                          const __bf16* __restrict__ dvT,
                                          const float* __restrict__ ksc,
                                          const float* __restrict__ mnorm,
                                          float* __restrict__ out) {
  __shared__ __bf16 As[128 * 32];
  __shared__ __bf16 Bs[128 * 32];
  int tid = threadIdx.x;
  int bid = blockIdx.x;
  if (bid == 384) {  // new_memory_norm (R4-proven pattern)
    int d = tid;
    float s = 0.f;
    for (int c = 0; c < NCHT; ++c) s += ksc[c * DMEM + d];
    out[(size_t)MTOT * HIDDEN + DMEM * DMEM + d] = mnorm[d] + s * (1.f / (float)BATCH);
    return;
  }
  int lane = tid & 63, wave = tid >> 6;
  int wr = wave >> 1, wc = wave & 1, quad = lane >> 4, l16 = lane & 15;
  if (bid < 256) {  // k6: output projection, 128x128
    int m0 = (bid & 31) * 128, by = bid >> 5;
    const __bf16* aptr = combb + (size_t)(m0 + (tid >> 2)) * DMEM + ((tid & 3) << 3);
    const __bf16* bptr = wob + (size_t)(by * 128 + (tid >> 2)) * DMEM + ((tid & 3) << 3);
    f32x4 acc[4][4] = {};
    for (int k0 = 0; k0 < DMEM; k0 += 32) {
      GL_LDS(aptr + k0, As + wave * 512);
      GL_LDS(aptr + (size_t)64 * DMEM + k0, As + 2048 + wave * 512);
      GL_LDS(bptr + k0, Bs + wave * 512);
      GL_LDS(bptr + (size_t)64 * DMEM + k0, Bs + 2048 + wave * 512);
      __syncthreads();
      bf16x8 aF[4], bF[4];
#pragma unroll
      for (int i = 0; i < 4; ++i)
        aF[i] = *reinterpret_cast<const bf16x8*>(As + (wr * 64 + i * 16 + l16) * 32 + quad * 8);
#pragma unroll
      for (int j = 0; j < 4; ++j)
        bF[j] = *reinterpret_cast<const bf16x8*>(Bs + (wc * 64 + j * 16 + l16) * 32 + quad * 8);
#pragma unroll
      for (int i = 0; i < 4; ++i)
#pragma unroll
        for (int j = 0; j < 4; ++j)
          acc[i][j] = __builtin_amdgcn_mfma_f32_16x16x32_bf16(aF[i], bF[j], acc[i][j], 0, 0, 0);
      __syncthreads();
    }
#pragma unroll
    for (int i = 0; i < 4; ++i)
#pragma unroll
      for (int j = 0; j < 4; ++j)
#pragma unroll
        for (int r = 0; r < 4; ++r) {
          int m = m0 + wr * 64 + i * 16 + quad * 4 + r;
          int n = by * 128 + wc * 64 + j * 16 + l16;
          out[(size_t)m * HIDDEN + n] = acc[i][j][r];
        }
  } else {  // k7b: memory_update split-K
    int t = bid - 256;
    int kbase = (t >> 3) * 256;
    int yy = t & 7;
    int d0 = (yy >> 1) * 64, e0 = (yy & 1) * 128;
    const __bf16* aptr = skT + (size_t)(d0 + (tid >> 2)) * MTOT + kbase + ((tid & 3) << 3);
    const __bf16* bptr = dvT + (size_t)(e0 + (tid >> 2)) * MTOT + kbase + ((tid & 3) << 3);
    f32x4 acc[2][4] = {};
    for (int k0 = 0; k0 < 256; k0 += 32) {
      GL_LDS(aptr + k0, As + wave * 512);
      GL_LDS(bptr + k0, Bs + wave * 512);
      GL_LDS(bptr + (size_t)64 * MTOT + k0, Bs + 2048 + wave * 512);
      __syncthreads();
      bf16x8 aF[2], bF[4];
#pragma unroll
      for (int i = 0; i < 2; ++i)
        aF[i] = *reinterpret_cast<const bf16x8*>(As + (wr * 32 + i * 16 + l16) * 32 + quad * 8);
#pragma unroll
      for (int j = 0; j < 4; ++j)
        bF[j] = *reinterpret_cast<const bf16x8*>(Bs + (wc * 64 + j * 16 + l16) * 32 + quad * 8);
#pragma unroll
      for (int i = 0; i < 2; ++i)
#pragma unroll
        for (int j = 0; j < 4; ++j)
          acc[i][j] = __builtin_amdgcn_mfma_f32_16x16x32_bf16(aF[i], bF[j], acc[i][j], 0, 0, 0);
      __syncthreads();
    }
    float* base = out + (size_t)MTOT * HIDDEN;
#pragma unroll
    for (int i = 0; i < 2; ++i)
#pragma unroll
      for (int j = 0; j < 4; ++j)
#pragma unroll
        for (int r = 0; r < 4; ++r) {
          int d = d0 + wr * 32 + i * 16 + quad * 4 + r;
          int e = e0 + wc * 64 + j * 16 + l16;
          atomicAdd(&base[(size_t)d * DMEM + e], acc[i][j][r] * (1.f / (float)MTOT));
        }
  }
}

extern "C" void kernel_launch(void* const* d_in, const int* in_sizes, int n_in,
                              void* d_out, int out_size, void* d_ws, size_t ws_size,
                              hipStream_t stream) {
  const float* hs = (const float*)d_in[0];
  const float* wq = (const float*)d_in[1];
  const float* wk = (const float*)d_in[2];
  const float* wv = (const float*)d_in[3];
  const float* wo = (const float*)d_in[4];
  const float* gate = (const float*)d_in[5];
  const float* mem = (const float*)d_in[6];
  const float* mnorm = (const float*)d_in[7];
  float* out = (float*)d_out;
  float* ws = (float*)d_ws;

  // fp32 region
  float* ksc = ws;              // 8192
  float* den = ksc + 8192;      // 4096
  float* qn = den + 4096;       // 4096
  float* kn = qn + 4096;        // 4096  (end: 20480 floats, 16B aligned)
  // bf16 region
  __bf16* kvcT = (__bf16*)(ws + 20480);               // 2097152
  __bf16* hsb = kvcT + (size_t)NCHT * DMEM * DMEM;    // 4194304
  __bf16* wqkvb = hsb + (size_t)MTOT * HIDDEN;        // 786432
  __bf16* wob = wqkvb + (size_t)3 * DMEM * HIDDEN;    // 262144
  __bf16* memT = wob + (size_t)HIDDEN * DMEM;         // 65536
  __bf16* sqb = memT + (size_t)DMEM * DMEM;           // 1048576
  __bf16* skb = sqb + (size_t)MTOT * DMEM;            // 1048576
  __bf16* skT = skb + (size_t)MTOT * DMEM;            // 1048576
  __bf16* vT = skT + (size_t)MTOT * DMEM;             // 1048576
  __bf16* scb = vT + (size_t)MTOT * DMEM;             // 524288
  __bf16* kvpT = scb + (size_t)NCHT * CHUNK * CHUNK;  // 2097152
  __bf16* combb = kvpT + (size_t)NCHT * DMEM * DMEM;  // 1048576
  __bf16* dvT = combb + (size_t)MTOT * DMEM;          // 1048576

  kprep<<<dim3(5200), 256, 0, stream>>>(hs, wq, wk, wv, wo, mem, hsb, wqkvb, wob, memT, out);
  k1_qkv_mfma<<<dim3(32, 6), 256, 0, stream>>>(hsb, wqkvb, sqb, skb, skT, vT);
  kC<<<dim3(NCHT, 11), 256, 0, stream>>>(vT, skT, sqb, skb, kvcT, scb, ksc);
  kD<<<dim3(2048), 256, 0, stream>>>(kvcT, kvpT, ksc, scb, sqb, skb, mnorm, den, qn, kn);
  kE<<<dim3(192), 256, 0, stream>>>(scb, sqb, skb, vT, kvpT, memT, den, qn, kn, gate, mnorm,
                                    combb, dvT);
  kF<<<dim3(385), 256, 0, stream>>>(combb, wob, skT, dvT, ksc, mnorm, out);
}